// Round 5
// baseline (3305.183 us; speedup 1.0000x reference)
//
#include <hip/hip_runtime.h>
#include <math.h>

typedef unsigned short u16;
using short8  = __attribute__((ext_vector_type(8))) short;
using float4v = __attribute__((ext_vector_type(4))) float;

__device__ __forceinline__ float b2f(u16 u) {
    union { unsigned int i; float f; } v; v.i = ((unsigned int)u) << 16; return v.f;
}
__device__ __forceinline__ u16 f2b(float f) {
    union { float f; unsigned int i; } v; v.f = f;
    unsigned int x = v.i;
    unsigned int r = (x + 0x7fffu + ((x >> 16) & 1u)) >> 16;
    return (u16)r;
}

#define GLOAD_LDS16(gp, lp) \
    __builtin_amdgcn_global_load_lds( \
        (const __attribute__((address_space(1))) unsigned int*)(gp), \
        (__attribute__((address_space(3))) unsigned int*)(lp), 16, 0, 0)

// ---------------------------------------------------------------------------
// weight f32 -> bf16 conversion (grid-stride)
// ---------------------------------------------------------------------------
__global__ __launch_bounds__(256) void wcvt(const float* __restrict__ s,
                                            u16* __restrict__ d, int n) {
    int stride = gridDim.x * 256;
    for (int i = blockIdx.x * 256 + threadIdx.x; i < n; i += stride)
        d[i] = f2b(s[i]);
}

// ---------------------------------------------------------------------------
// mix_shift: out[i,d] = f[d]*xn_i[d] + (1-f[d])*xn_{i-1}[d]  (bf16 out)
// ---------------------------------------------------------------------------
__global__ __launch_bounds__(256) void mix_shift(const float* __restrict__ src,
                                                 const float* __restrict__ w,
                                                 const float* __restrict__ f,
                                                 u16* __restrict__ out) {
    __shared__ float redc[256], redp[256];
    int tid = threadIdx.x;
    size_t i = blockIdx.x;
    size_t ip = ((i & 4095) == 0) ? i : i - 1;
    float xc[4], xp[4];
    float ssc = 0.f, ssp = 0.f;
#pragma unroll
    for (int l = 0; l < 4; ++l) {
        int d = tid + l * 256;
        xc[l] = src[i * 1024 + d];  ssc += xc[l] * xc[l];
        xp[l] = src[ip * 1024 + d]; ssp += xp[l] * xp[l];
    }
    redc[tid] = ssc; redp[tid] = ssp; __syncthreads();
    for (int st = 128; st > 0; st >>= 1) {
        if (tid < st) { redc[tid] += redc[tid + st]; redp[tid] += redp[tid + st]; }
        __syncthreads();
    }
    float ic  = 1.f / (sqrtf(redc[0]) * (1.f / 32.f) + 1e-8f);
    float ipv = 1.f / (sqrtf(redp[0]) * (1.f / 32.f) + 1e-8f);
#pragma unroll
    for (int l = 0; l < 4; ++l) {
        int d = tid + l * 256;
        float wd = w[d], fd = f[d];
        float xn = wd * xc[l] * ic;
        float xx = wd * xp[l] * ipv;
        out[i * 1024 + d] = f2b(fd * xn + (1.f - fd) * xx);
    }
}

// ---------------------------------------------------------------------------
// kproj (f64 compute, f32 store in transposed Kt4 layout [b][g][key][4]).
// Also stores invn[j] (f32). Identical numerics to the passing round-4 kernel.
// ---------------------------------------------------------------------------
__global__ __launch_bounds__(256) void kproj(const float* __restrict__ x,
                                             const float* __restrict__ w1,
                                             const float* __restrict__ kw,
                                             const float* __restrict__ kb,
                                             float* __restrict__ Kt4,
                                             float* __restrict__ invn) {
    __shared__ double xk[1024];
    __shared__ double red[256];
    int tid = threadIdx.x;
    size_t j = blockIdx.x;
    double ss = 0.0;
    float xc[4];
#pragma unroll
    for (int l = 0; l < 4; ++l) {
        int d = tid + l * 256;
        xc[l] = x[j * 1024 + d];
        ss += (double)xc[l] * (double)xc[l];
    }
    red[tid] = ss; __syncthreads();
    for (int st = 128; st > 0; st >>= 1) {
        if (tid < st) red[tid] += red[tid + st];
        __syncthreads();
    }
    double inv = 1.0 / (sqrt(red[0]) * (1.0 / 32.0) + 1e-8);
#pragma unroll
    for (int l = 0; l < 4; ++l) {
        int d = tid + l * 256;
        xk[d] = (double)w1[d] * (double)xc[l] * inv;
    }
    __syncthreads();
    int wv = tid >> 6, lane = tid & 63;
    int b = (int)(j >> 12), jj = (int)(j & 4095);
    for (int it = 0; it < 16; ++it) {
        int a = wv * 16 + it;
        const float* kr = kw + (size_t)a * 1024;
        double p = 0.0;
#pragma unroll
        for (int m = 0; m < 16; ++m) p += xk[lane + 64 * m] * (double)kr[lane + 64 * m];
        for (int off = 32; off; off >>= 1) p += __shfl_xor(p, off);
        if (lane == 0)
            Kt4[(((size_t)b * 16 + (a >> 2)) * 4096 + jj) * 4 + (a & 3)] = (float)(p + (double)kb[a]);
    }
    if (tid == 0) invn[j] = (float)inv;
}

// ---------------------------------------------------------------------------
// attn2: 2 query rows per block. f64 Q projection; f32 scores (stage-1
// top-36, 2 barriers/iter); f64 rescore of the 36 candidates -> exact top-32
// (same selection numerics as the passing kernel); f64 softmax; f32 gather.
// ---------------------------------------------------------------------------
__global__ __launch_bounds__(256) void attn2(const float* __restrict__ x,
                                             const float* __restrict__ w1,
                                             const float* __restrict__ qw,
                                             const float* __restrict__ qb,
                                             const float* __restrict__ Kt4,
                                             const float* __restrict__ invn,
                                             u16* __restrict__ y) {
    __shared__ float  sc[2][4096];     // 32 KB; phase-A alias: xq64 (sc[0]), red (sc[1])
    __shared__ double qv64[2][64];
    __shared__ float  qv32[2][64];
    __shared__ float  rvv[4];
    __shared__ int    rii[4];
    __shared__ int    winIdx;
    __shared__ int    cand[2][36];
    __shared__ double s2v[2][36];
    __shared__ int    topi[2][32];
    __shared__ double s2sel[2][32];
    __shared__ float  pw[2][32];

    int tid = threadIdx.x;
    int i0 = blockIdx.x * 2, i1 = i0 + 1;
    int b = i0 >> 12;
    int base = b << 12;
    int wv = tid >> 6, lane = tid & 63;

    // ---- phase A: norms + xn (f64) ----
    double* xq64 = (double*)&sc[0][0];          // [2][1024]
    double* red  = (double*)&sc[1][0];          // [2][256]
    float xc0[4], xc1[4];
    double ss0 = 0.0, ss1 = 0.0;
#pragma unroll
    for (int l = 0; l < 4; ++l) {
        int d = tid + l * 256;
        xc0[l] = x[(size_t)i0 * 1024 + d]; ss0 += (double)xc0[l] * (double)xc0[l];
        xc1[l] = x[(size_t)i1 * 1024 + d]; ss1 += (double)xc1[l] * (double)xc1[l];
    }
    red[tid] = ss0; red[256 + tid] = ss1; __syncthreads();
    for (int st = 128; st > 0; st >>= 1) {
        if (tid < st) { red[tid] += red[tid + st]; red[256 + tid] += red[256 + tid + st]; }
        __syncthreads();
    }
    double inv0 = 1.0 / (sqrt(red[0])   * (1.0 / 32.0) + 1e-8);
    double inv1 = 1.0 / (sqrt(red[256]) * (1.0 / 32.0) + 1e-8);
    __syncthreads();   // red reads done before xq64 writes into same region family
#pragma unroll
    for (int l = 0; l < 4; ++l) {
        int d = tid + l * 256;
        double wd = (double)w1[d];
        xq64[d]        = wd * (double)xc0[l] * inv0;
        xq64[1024 + d] = wd * (double)xc1[l] * inv1;
    }
    __syncthreads();

    // ---- Q projection (f64) for both rows ----
    for (int it = 0; it < 16; ++it) {
        int a = wv * 16 + it;
        const float* qr = qw + (size_t)a * 1024;
        double p0 = 0.0, p1 = 0.0;
#pragma unroll
        for (int m = 0; m < 16; ++m) {
            int idx = lane + (m << 6);
            double wq = (double)qr[idx];
            p0 += xq64[idx] * wq;
            p1 += xq64[1024 + idx] * wq;
        }
        for (int off = 32; off; off >>= 1) { p0 += __shfl_xor(p0, off); p1 += __shfl_xor(p1, off); }
        if (lane == 0) {
            double q0 = p0 + (double)qb[a], q1 = p1 + (double)qb[a];
            qv64[0][a] = q0; qv32[0][a] = (float)q0;
            qv64[1][a] = q1; qv32[1][a] = (float)q1;
        }
    }
    __syncthreads();   // xq64 dead; sc reusable

    // ---- phase B: f32 scores, coalesced Kt4 reads ----
    const float4* Kt4v = (const float4*)(Kt4 + (size_t)b * 16 * 4096 * 4);
#pragma unroll 1
    for (int l = 0; l < 16; ++l) {
        int j = tid + (l << 8);
        float a0 = 0.f, a1 = 0.f;
#pragma unroll
        for (int g = 0; g < 16; ++g) {
            float4 kv = Kt4v[g * 4096 + j];
            float4 q0 = *(const float4*)&qv32[0][g * 4];
            float4 q1 = *(const float4*)&qv32[1][g * 4];
            a0 += q0.x * kv.x + q0.y * kv.y + q0.z * kv.z + q0.w * kv.w;
            a1 += q1.x * kv.x + q1.y * kv.y + q1.z * kv.z + q1.w * kv.w;
        }
        a0 *= 0.125f; a1 *= 0.125f;
        sc[0][j] = (a0 == a0) ? a0 : -3e38f;
        sc[1][j] = (a1 == a1) ? a1 : -3e38f;
    }
    __syncthreads();

    // ---- phase C: stage-1 top-36 per row (cached local max, 2 barriers/iter)
    for (int r = 0; r < 2; ++r) {
        float lv = -3.4e38f; int li = 0x7fffffff;
        for (int l = 0; l < 16; ++l) {
            int j = tid + (l << 8); float v = sc[r][j];
            if (v > lv) { lv = v; li = j; }
        }
        for (int it = 0; it < 36; ++it) {
            float mv = lv; int mi = li;
#pragma unroll
            for (int off = 1; off < 64; off <<= 1) {
                float ov = __shfl_xor(mv, off); int oi = __shfl_xor(mi, off);
                if (ov > mv || (ov == mv && oi < mi)) { mv = ov; mi = oi; }
            }
            if (lane == 0) { rvv[wv] = mv; rii[wv] = mi; }
            __syncthreads();
            if (tid == 0) {
                float bv = rvv[0]; int bi = rii[0];
                for (int w = 1; w < 4; ++w)
                    if (rvv[w] > bv || (rvv[w] == bv && rii[w] < bi)) { bv = rvv[w]; bi = rii[w]; }
                winIdx = bi; cand[r][it] = bi;
            }
            __syncthreads();
            int widx = winIdx;
            if (tid == (widx & 255)) {
                sc[r][widx] = -3.4e38f;
                lv = -3.4e38f; li = 0x7fffffff;
                for (int l = 0; l < 16; ++l) {
                    int j = tid + (l << 8); float v = sc[r][j];
                    if (v > lv) { lv = v; li = j; }
                }
            }
        }
    }
    __syncthreads();

    // ---- stage-2: f64 rescore of 36 candidates per row ----
    if (tid < 144) {
        int r = tid / 72, u = tid - r * 72, c = u >> 1, h = u & 1;
        int j = cand[r][c];
        double p = 0.0;
        int d0 = h * 32;
#pragma unroll
        for (int d = 0; d < 32; ++d) {
            int dd = d0 + d;
            float kf = Kt4[(((size_t)b * 16 + (dd >> 2)) * 4096 + j) * 4 + (dd & 3)];
            p += qv64[r][dd] * (double)kf;
        }
        p += __shfl_xor(p, 1);
        if (h == 0) s2v[r][c] = p * 0.125;
    }
    __syncthreads();

    // ---- exact top-32 among 36 (wave 0 -> row 0, wave 1 -> row 1) ----
    if (tid < 128) {
        int r = tid >> 6; int ln = tid & 63;
        double v; int idx;
        if (ln < 36) { v = s2v[r][ln]; idx = cand[r][ln]; }
        else         { v = -1e300;     idx = 0x7fffffff; }
        for (int it = 0; it < 32; ++it) {
            double mv = v; int mi = idx;
#pragma unroll
            for (int off = 1; off < 64; off <<= 1) {
                double ov = __shfl_xor(mv, off); int oi = __shfl_xor(mi, off);
                if (ov > mv || (ov == mv && oi < mi)) { mv = ov; mi = oi; }
            }
            if (ln == 0) { topi[r][it] = mi; s2sel[r][it] = mv; }
            if (idx == mi) v = -1e300;
        }
    }
    __syncthreads();

    // ---- softmax (f64) + invn scaling ----
    if (tid < 64) {
        int r = tid >> 5, k = tid & 31;
        double m = s2sel[r][0];
        double e = exp(s2sel[r][k] - m);
        double s = e;
#pragma unroll
        for (int off = 1; off < 32; off <<= 1) s += __shfl_xor(s, off);
        pw[r][k] = (float)(e / s) * invn[base + topi[r][k]];
    }
    __syncthreads();

    // ---- gather: y = w1 .* sum_k p_k * x_row(k) ----
    float a0[4] = {0.f, 0.f, 0.f, 0.f}, a1[4] = {0.f, 0.f, 0.f, 0.f};
    for (int k = 0; k < 32; ++k) {
        float p0 = pw[0][k], p1 = pw[1][k];
        const float* xr0 = x + (size_t)(base + topi[0][k]) * 1024;
        const float* xr1 = x + (size_t)(base + topi[1][k]) * 1024;
#pragma unroll
        for (int l = 0; l < 4; ++l) {
            int d = tid + l * 256;
            a0[l] += p0 * xr0[d];
            a1[l] += p1 * xr1[d];
        }
    }
#pragma unroll
    for (int l = 0; l < 4; ++l) {
        int d = tid + l * 256;
        float wd = w1[d];
        y[(size_t)i0 * 1024 + d] = f2b(wd * a0[l]);
        y[(size_t)i1 * 1024 + d] = f2b(wd * a1[l]);
    }
}

// ---------------------------------------------------------------------------
// MFMA bf16 GEMM: C[M,N] = A[M,K] @ B[N,K]^T. 128x128 tile, BK=64,
// 4 waves (2x2 of 64x64), 16x16x32 MFMA, global_load_lds width-16 staging.
// EPI: 0 = bf16(acc + f32 bias[col])
//      1 = bf16(acc + bf16 aux0[g])              (in-place-safe)
//      2 = bf16(sigmoid(acc) * bf16 aux0[g])     (in-place-safe)
//      3 = f32: outF[g] = acc + f32 auxF[g]
//      4 = bf16(sigmoid(acc))
//      5 = bf16(relu(acc)^2)
//      6 = f32: outF[g] += bf16(aux0[g]) * acc   (read-modify-write)
// ---------------------------------------------------------------------------
template <int EPI>
__global__ __launch_bounds__(256) void gemm_bt(const u16* __restrict__ A,
                                               const u16* __restrict__ B,
                                               u16* outB, float* outF,
                                               const float* __restrict__ biasF,
                                               const u16* aux0,
                                               const float* auxF,
                                               int N, int K, int lda, int ldb) {
    __shared__ u16 As[128 * 64];
    __shared__ u16 Bs[128 * 64];
    int tid = threadIdx.x;
    int lane = tid & 63;
    int wv = tid >> 6;
    int row0 = blockIdx.y * 128;
    int col0 = blockIdx.x * 128;
    int wm = (wv >> 1) * 64;
    int wn = (wv & 1) * 64;
    int frow = lane & 15, quad = lane >> 4;

    float4v zero = {0.f, 0.f, 0.f, 0.f};
    float4v acc[4][4];
#pragma unroll
    for (int i = 0; i < 4; ++i)
#pragma unroll
        for (int j = 0; j < 4; ++j) acc[i][j] = zero;

    for (int k0 = 0; k0 < K; k0 += 64) {
#pragma unroll
        for (int it = 0; it < 4; ++it) {
            int base = (wv * 4 + it) * 512;      // element offset (wave-uniform)
            int e = base + lane * 8;
            int r = e >> 6, c = e & 63;
            GLOAD_LDS16(A + (size_t)(row0 + r) * lda + (k0 + c), &As[base]);
            GLOAD_LDS16(B + (size_t)(col0 + r) * ldb + (k0 + c), &Bs[base]);
        }
        __syncthreads();
#pragma unroll
        for (int kk = 0; kk < 64; kk += 32) {
            short8 a_frag[4], b_frag[4];
#pragma unroll
            for (int mi = 0; mi < 4; ++mi)
                a_frag[mi] = *(const short8*)&As[(wm + mi * 16 + frow) * 64 + kk + quad * 8];
#pragma unroll
            for (int ni = 0; ni < 4; ++ni)
                b_frag[ni] = *(const short8*)&Bs[(wn + ni * 16 + frow) * 64 + kk + quad * 8];
#pragma unroll
            for (int mi = 0; mi < 4; ++mi)
#pragma unroll
                for (int ni = 0; ni < 4; ++ni)
                    acc[mi][ni] = __builtin_amdgcn_mfma_f32_16x16x32_bf16(
                        a_frag[mi], b_frag[ni], acc[mi][ni], 0, 0, 0);
        }
        __syncthreads();
    }

#pragma unroll
    for (int mi = 0; mi < 4; ++mi) {
#pragma unroll
        for (int ni = 0; ni < 4; ++ni) {
#pragma unroll
            for (int r = 0; r < 4; ++r) {
                int row = row0 + wm + mi * 16 + quad * 4 + r;
                int col = col0 + wn + ni * 16 + frow;
                size_t g = (size_t)row * N + col;
                float v = acc[mi][ni][r];
                if constexpr (EPI == 0) {
                    outB[g] = f2b(v + biasF[col]);
                } else if constexpr (EPI == 1) {
                    outB[g] = f2b(v + b2f(aux0[g]));
                } else if constexpr (EPI == 2) {
                    float sg = 1.f / (1.f + expf(-v));
                    outB[g] = f2b(sg * b2f(aux0[g]));
                } else if constexpr (EPI == 3) {
                    outF[g] = v + auxF[g];
                } else if constexpr (EPI == 4) {
                    outB[g] = f2b(1.f / (1.f + expf(-v)));
                } else if constexpr (EPI == 5) {
                    float t = v > 0.f ? v : 0.f;
                    outB[g] = f2b(t * t);
                } else if constexpr (EPI == 6) {
                    outF[g] = outF[g] + b2f(aux0[g]) * v;
                }
            }
        }
    }
}

__global__ __launch_bounds__(256) void copy_f32(const float4* __restrict__ src,
                                                float4* __restrict__ dst) {
    size_t g = (size_t)blockIdx.x * 256 + threadIdx.x;
    dst[g] = src[g];
}

// ---------------------------------------------------------------------------
extern "C" void kernel_launch(void* const* d_in, const int* in_sizes, int n_in,
                              void* d_out, int out_size, void* d_ws, size_t ws_size,
                              hipStream_t stream) {
    (void)in_sizes; (void)n_in; (void)out_size; (void)ws_size;
    const float* x   = (const float*)d_in[0];
    const float* n1w = (const float*)d_in[1];
    // d_in[2] tm_mix_k, d_in[5] tm_key_w are dead in the reference
    const float* tmv = (const float*)d_in[3];
    const float* tmr = (const float*)d_in[4];
    const float* vw  = (const float*)d_in[6];
    const float* rw  = (const float*)d_in[7];
    const float* ow  = (const float*)d_in[8];
    const float* qw  = (const float*)d_in[9];
    const float* qb  = (const float*)d_in[10];
    const float* skw = (const float*)d_in[11];
    const float* skb = (const float*)d_in[12];
    const float* svw = (const float*)d_in[13];
    const float* svb = (const float*)d_in[14];
    const float* sow = (const float*)d_in[15];
    const float* sob = (const float*)d_in[16];
    const float* n2w = (const float*)d_in[17];
    const float* cmk = (const float*)d_in[18];
    const float* cmr = (const float*)d_in[19];
    const float* ckw = (const float*)d_in[20];
    const float* crw = (const float*)d_in[21];
    const float* cvw = (const float*)d_in[22];

    char* W = (char*)d_ws;
    const size_t MB = 1ull << 20;
    u16*   wsA   = (u16*)(W + 0 * MB);     // 16 MB bf16 activations
    u16*   wsB   = (u16*)(W + 16 * MB);    // 16 MB bf16 activations
    float* x1    = (float*)(W + 32 * MB);  // 32 MB f32
    float* Kt4   = (float*)(W + 64 * MB);  // 2 MB f32  [b][g][key][4]
    float* invn  = (float*)(W + 66 * MB);  // 32 KB
    u16*   ckw16 = (u16*)(W + 68 * MB);    // 8 MB
    u16*   cvw16 = (u16*)(W + 76 * MB);    // 8 MB
    u16*   svw16 = (u16*)(W + 84 * MB);    // 2 MB  (dead by channel phase)
    u16*   sow16 = (u16*)(W + 86 * MB);
    u16*   vw16  = (u16*)(W + 88 * MB);
    u16*   rw16  = (u16*)(W + 90 * MB);
    u16*   ow16  = (u16*)(W + 92 * MB);
    u16*   chunk = (u16*)(W + 84 * MB);    // 16 MB (channel phase, overlays svw..ow16)
    u16*   crw16 = (u16*)(W + 100 * MB);   // 2 MB  -> peak usage 102 MB
    float* out   = (float*)d_out;

    dim3 blk(256);
    dim3 gN1024(8, 64);
    const int NW = 512;

    // weight conversions f32 -> bf16
    wcvt<<<NW, blk, 0, stream>>>(svw, svw16, 1024 * 1024);
    wcvt<<<NW, blk, 0, stream>>>(sow, sow16, 1024 * 1024);
    wcvt<<<NW, blk, 0, stream>>>(vw,  vw16,  1024 * 1024);
    wcvt<<<NW, blk, 0, stream>>>(rw,  rw16,  1024 * 1024);
    wcvt<<<NW, blk, 0, stream>>>(ow,  ow16,  1024 * 1024);
    wcvt<<<NW, blk, 0, stream>>>(crw, crw16, 1024 * 1024);
    wcvt<<<NW, blk, 0, stream>>>(ckw, ckw16, 4096 * 1024);
    wcvt<<<NW, blk, 0, stream>>>(cvw, cvw16, 1024 * 4096);

    // --- time-mix ---
    kproj<<<8192, blk, 0, stream>>>(x, n1w, skw, skb, Kt4, invn);
    attn2<<<4096, blk, 0, stream>>>(x, n1w, qw, qb, Kt4, invn, wsB);  // y
    // t = y @ sa_v_w^T + svb
    gemm_bt<0><<<gN1024, blk, 0, stream>>>(wsB, svw16, wsA, nullptr, svb, nullptr, nullptr, 1024, 1024, 1024, 1024);
    // attnO = t @ sa_o_w^T + sob
    gemm_bt<0><<<gN1024, blk, 0, stream>>>(wsA, sow16, wsB, nullptr, sob, nullptr, nullptr, 1024, 1024, 1024, 1024);
    // vin
    mix_shift<<<8192, blk, 0, stream>>>(x, n1w, tmv, wsA);
    // z = vin @ tm_value_w^T + attnO   (in-place over attnO in wsB)
    gemm_bt<1><<<gN1024, blk, 0, stream>>>(wsA, vw16, wsB, nullptr, nullptr, wsB, nullptr, 1024, 1024, 1024, 1024);
    // rin
    mix_shift<<<8192, blk, 0, stream>>>(x, n1w, tmr, wsA);
    // rkv = sigmoid(rin @ tm_recept_w^T) * z   (in-place over z in wsB)
    gemm_bt<2><<<gN1024, blk, 0, stream>>>(wsA, rw16, wsB, nullptr, nullptr, wsB, nullptr, 1024, 1024, 1024, 1024);
    // x1 = x + rkv @ tm_out_w^T   (f32)
    gemm_bt<3><<<gN1024, blk, 0, stream>>>(wsB, ow16, nullptr, x1, nullptr, nullptr, x, 1024, 1024, 1024, 1024);

    // --- channel-mix ---
    mix_shift<<<8192, blk, 0, stream>>>(x1, n2w, cmr, wsA);   // rin2
    gemm_bt<4><<<gN1024, blk, 0, stream>>>(wsA, crw16, wsB, nullptr, nullptr, nullptr, nullptr, 1024, 1024, 1024, 1024);
    mix_shift<<<8192, blk, 0, stream>>>(x1, n2w, cmk, wsA);   // kin2
    for (int c = 0; c < 4; ++c) {
        const u16* ckw_c = ckw16 + (size_t)c * 1024 * 1024;  // rows c*1024..+1024 of (4096,1024)
        const u16* cvw_c = cvw16 + (size_t)c * 1024;         // cols c*1024..+1024 of (1024,4096)
        gemm_bt<5><<<gN1024, blk, 0, stream>>>(wsA, ckw_c, chunk, nullptr, nullptr, nullptr, nullptr,
                                               1024, 1024, 1024, 1024);
        gemm_bt<6><<<gN1024, blk, 0, stream>>>(chunk, cvw_c, nullptr, x1, nullptr, wsB, nullptr,
                                               1024, 1024, 1024, 4096);
    }
    // final: out = x1
    copy_f32<<<8192, blk, 0, stream>>>((const float4*)x1, (float4*)d_out);
}

// Round 6
// 1765.806 us; speedup vs baseline: 1.8718x; 1.8718x over previous
//
#include <hip/hip_runtime.h>
#include <math.h>

typedef unsigned short u16;
using short8  = __attribute__((ext_vector_type(8))) short;
using float4v = __attribute__((ext_vector_type(4))) float;

__device__ __forceinline__ float b2f(u16 u) {
    union { unsigned int i; float f; } v; v.i = ((unsigned int)u) << 16; return v.f;
}
__device__ __forceinline__ u16 f2b(float f) {
    union { float f; unsigned int i; } v; v.f = f;
    unsigned int x = v.i;
    unsigned int r = (x + 0x7fffu + ((x >> 16) & 1u)) >> 16;
    return (u16)r;
}

#define GLOAD_LDS16(gp, lp) \
    __builtin_amdgcn_global_load_lds( \
        (const __attribute__((address_space(1))) unsigned int*)(gp), \
        (__attribute__((address_space(3))) unsigned int*)(lp), 16, 0, 0)

// ---------------------------------------------------------------------------
__global__ __launch_bounds__(256) void wcvt(const float* __restrict__ s,
                                            u16* __restrict__ d, int n) {
    int stride = gridDim.x * 256;
    for (int i = blockIdx.x * 256 + threadIdx.x; i < n; i += stride)
        d[i] = f2b(s[i]);
}

// qw[64][1024] -> qwT4[d>>2][a][d&3]  (lane-coalesced float4 per 4 dims)
__global__ __launch_bounds__(256) void prep_qwT4(const float* __restrict__ qw,
                                                 float* __restrict__ qwT4) {
    int idx = blockIdx.x * 256 + threadIdx.x;   // 65536
    int a = idx >> 10, d = idx & 1023;
    qwT4[(size_t)(d >> 2) * 256 + a * 4 + (d & 3)] = qw[idx];
}

// ---------------------------------------------------------------------------
// mix_shift: out[i,d] = f[d]*xn_i[d] + (1-f[d])*xn_{i-1}[d]  (bf16 out)
// ---------------------------------------------------------------------------
__global__ __launch_bounds__(256) void mix_shift(const float* __restrict__ src,
                                                 const float* __restrict__ w,
                                                 const float* __restrict__ f,
                                                 u16* __restrict__ out) {
    __shared__ float redc[256], redp[256];
    int tid = threadIdx.x;
    size_t i = blockIdx.x;
    size_t ip = ((i & 4095) == 0) ? i : i - 1;
    float xc[4], xp[4];
    float ssc = 0.f, ssp = 0.f;
#pragma unroll
    for (int l = 0; l < 4; ++l) {
        int d = tid + l * 256;
        xc[l] = src[i * 1024 + d];  ssc += xc[l] * xc[l];
        xp[l] = src[ip * 1024 + d]; ssp += xp[l] * xp[l];
    }
    redc[tid] = ssc; redp[tid] = ssp; __syncthreads();
    for (int st = 128; st > 0; st >>= 1) {
        if (tid < st) { redc[tid] += redc[tid + st]; redp[tid] += redp[tid + st]; }
        __syncthreads();
    }
    float ic  = 1.f / (sqrtf(redc[0]) * (1.f / 32.f) + 1e-8f);
    float ipv = 1.f / (sqrtf(redp[0]) * (1.f / 32.f) + 1e-8f);
#pragma unroll
    for (int l = 0; l < 4; ++l) {
        int d = tid + l * 256;
        float wd = w[d], fd = f[d];
        float xn = wd * xc[l] * ic;
        float xx = wd * xp[l] * ipv;
        out[i * 1024 + d] = f2b(fd * xn + (1.f - fd) * xx);
    }
}

// ---------------------------------------------------------------------------
// kproj (f64 compute, f32 store in transposed Kt4 layout [b][g][key][4]).
// Also stores invn[j] (f32).
// ---------------------------------------------------------------------------
__global__ __launch_bounds__(256) void kproj(const float* __restrict__ x,
                                             const float* __restrict__ w1,
                                             const float* __restrict__ kw,
                                             const float* __restrict__ kb,
                                             float* __restrict__ Kt4,
                                             float* __restrict__ invn) {
    __shared__ double xk[1024];
    __shared__ double red[256];
    int tid = threadIdx.x;
    size_t j = blockIdx.x;
    double ss = 0.0;
    float xc[4];
#pragma unroll
    for (int l = 0; l < 4; ++l) {
        int d = tid + l * 256;
        xc[l] = x[j * 1024 + d];
        ss += (double)xc[l] * (double)xc[l];
    }
    red[tid] = ss; __syncthreads();
    for (int st = 128; st > 0; st >>= 1) {
        if (tid < st) red[tid] += red[tid + st];
        __syncthreads();
    }
    double inv = 1.0 / (sqrt(red[0]) * (1.0 / 32.0) + 1e-8);
#pragma unroll
    for (int l = 0; l < 4; ++l) {
        int d = tid + l * 256;
        xk[d] = (double)w1[d] * (double)xc[l] * inv;
    }
    __syncthreads();
    int wv = tid >> 6, lane = tid & 63;
    int b = (int)(j >> 12), jj = (int)(j & 4095);
    for (int it = 0; it < 16; ++it) {
        int a = wv * 16 + it;
        const float* kr = kw + (size_t)a * 1024;
        double p = 0.0;
#pragma unroll
        for (int m = 0; m < 16; ++m) p += xk[lane + 64 * m] * (double)kr[lane + 64 * m];
        for (int off = 32; off; off >>= 1) p += __shfl_xor(p, off);
        if (lane == 0)
            Kt4[(((size_t)b * 16 + (a >> 2)) * 4096 + jj) * 4 + (a & 3)] = (float)(p + (double)kb[a]);
    }
    if (tid == 0) invn[j] = (float)inv;
}

// ---------------------------------------------------------------------------
// attn_w: one WAVE per query row, zero __syncthreads. 128-thr blocks = 2
// independent waves = 2 rows. Per wave: f64 Q-proj (coalesced qwT4), f32
// scores into private LDS slice, stage-1 top-40 via shuffle-reduce with
// per-lane cached top-2 (rescan only on 2nd win), f64 rescore of the 40
// candidates, rank-by-broadcast -> exact top-32 (tie: lower key index),
// f64 softmax, coalesced gather  y = w1 .* sum p_k inv_k x_k.
// ---------------------------------------------------------------------------
__global__ __launch_bounds__(128, 2) void attn_w(const float* __restrict__ x,
                                                 const float* __restrict__ w1,
                                                 const float* __restrict__ qwT4,
                                                 const float* __restrict__ qb,
                                                 const float* __restrict__ Kt4,
                                                 const float* __restrict__ invn,
                                                 u16* __restrict__ y) {
    __shared__ float  sc[2][4096];
    __shared__ double qv64s[2][64];
    __shared__ float  qv32s[2][64];
    __shared__ int    candL[2][40];
    __shared__ float  pwL[2][32];
    __shared__ int    idxL[2][32];

    int tid = threadIdx.x;
    int w = tid >> 6, lane = tid & 63;
    int i = blockIdx.x * 2 + w;
    int b = i >> 12;
    int base = b << 12;

    // ---- Q projection: lane a computes Q[a] (f64 accumulate) ----
    const float* xr = x + (size_t)i * 1024;
    double q = 0.0;
    for (int d4 = 0; d4 < 256; ++d4) {
        float4 w4  = *(const float4*)(w1 + d4 * 4);
        float4 x4  = *(const float4*)(xr + d4 * 4);
        float4 qw4 = *(const float4*)(qwT4 + (size_t)d4 * 256 + lane * 4);
        q += (double)(w4.x * x4.x) * (double)qw4.x;
        q += (double)(w4.y * x4.y) * (double)qw4.y;
        q += (double)(w4.z * x4.z) * (double)qw4.z;
        q += (double)(w4.w * x4.w) * (double)qw4.w;
    }
    q = q * (double)invn[i] + (double)qb[lane];
    qv64s[w][lane] = q;
    qv32s[w][lane] = (float)q;
    // (same-wave LDS ordering: later reads see these writes; no barrier needed)

    float4 qreg[16];
#pragma unroll
    for (int g = 0; g < 16; ++g) qreg[g] = *(const float4*)&qv32s[w][g * 4];

    // ---- f32 scores (coalesced Kt4 reads), per-lane top-2 tracking ----
    const float4* K4 = (const float4*)Kt4 + (size_t)b * 16 * 4096;
    float lv1 = -3.4e38f, lv2 = -3.4e38f;
    int   li1 = 0x7ffffffe, li2 = 0x7fffffff;
    for (int t = 0; t < 64; ++t) {
        int j = t * 64 + lane;
        float s = 0.f;
#pragma unroll
        for (int g = 0; g < 16; ++g) {
            float4 kv = K4[g * 4096 + j];
            s += qreg[g].x * kv.x + qreg[g].y * kv.y + qreg[g].z * kv.z + qreg[g].w * kv.w;
        }
        s *= 0.125f;
        if (!(s == s)) s = -3.3e38f;   // NaN insurance
        sc[w][j] = s;
        if (s > lv1 || (s == lv1 && j < li1)) { lv2 = lv1; li2 = li1; lv1 = s; li1 = j; }
        else if (s > lv2 || (s == lv2 && j < li2)) { lv2 = s; li2 = j; }
    }

    // ---- stage-1: extract top-40 (shuffle-only; no barriers) ----
    bool v2ok = true;
    for (int it = 0; it < 40; ++it) {
        float mv = lv1; int mi = li1;
#pragma unroll
        for (int off = 32; off >= 1; off >>= 1) {
            float ov = __shfl_xor(mv, off); int oi = __shfl_xor(mi, off);
            if (ov > mv || (ov == mv && oi < mi)) { mv = ov; mi = oi; }
        }
        if (lane == 0) candL[w][it] = mi;
        if (li1 == mi) {                    // this lane owned the winner
            sc[w][mi] = -3.4e38f;
            if (v2ok) { lv1 = lv2; li1 = li2; v2ok = false; }
            else {                           // rescan own 64 slots, fresh top-2
                lv1 = -3.4e38f; li1 = 0x7ffffffe; lv2 = -3.4e38f; li2 = 0x7fffffff;
                for (int t = 0; t < 64; ++t) {
                    int j = t * 64 + lane;
                    float v = sc[w][j];
                    if (v > lv1 || (v == lv1 && j < li1)) { lv2 = lv1; li2 = li1; lv1 = v; li1 = j; }
                    else if (v > lv2 || (v == lv2 && j < li2)) { lv2 = v; li2 = j; }
                }
                v2ok = true;
            }
        }
    }

    // ---- stage-2: f64 rescore of the 40 candidates ----
    int c = (lane < 40) ? lane : 0;
    int j = candL[w][c];
    double s = 0.0;
#pragma unroll
    for (int g = 0; g < 16; ++g) {
        float4 kv = K4[g * 4096 + j];
        s += qv64s[w][4 * g + 0] * (double)kv.x + qv64s[w][4 * g + 1] * (double)kv.y
           + qv64s[w][4 * g + 2] * (double)kv.z + qv64s[w][4 * g + 3] * (double)kv.w;
    }
    s *= 0.125;
    if (lane >= 40) { s = -1.0e300; j = 0x7fffffff; }

    // ---- exact rank among the 40 (tie -> lower key index) ----
    int rank = 0;
    for (int c2 = 0; c2 < 40; ++c2) {
        double s2 = __shfl(s, c2); int j2 = __shfl(j, c2);
        if (s2 > s || (s2 == s && j2 < j)) ++rank;
    }

    // ---- f64 softmax over ranks 0..31 ----
    unsigned long long m0 = __ballot(rank == 0);
    int src = __ffsll((unsigned long long)m0) - 1;
    double mx = __shfl(s, src);
    double e = (rank < 32) ? exp(s - mx) : 0.0;
    double sum = e;
#pragma unroll
    for (int off = 1; off < 64; off <<= 1) sum += __shfl_xor(sum, off);
    if (rank < 32) {
        pwL[w][rank] = (float)(e / sum) * invn[base + j];
        idxL[w][rank] = j;
    }

    // ---- gather: y = w1 .* sum_k p_k * x_row(k) ----
    float acc[16];
#pragma unroll
    for (int m = 0; m < 16; ++m) acc[m] = 0.f;
    for (int k = 0; k < 32; ++k) {
        float p = pwL[w][k]; int jx = idxL[w][k];
        const float* xg = x + (size_t)(base + jx) * 1024;
#pragma unroll
        for (int m = 0; m < 16; ++m) acc[m] += p * xg[m * 64 + lane];
    }
#pragma unroll
    for (int m = 0; m < 16; ++m) {
        int d = m * 64 + lane;
        y[(size_t)i * 1024 + d] = f2b(w1[d] * acc[m]);
    }
}

// ---------------------------------------------------------------------------
// MFMA bf16 GEMM: C[M,N] = A[M,K] @ B[N,K]^T. 128x128 tile, BK=64,
// 4 waves (2x2 of 64x64), 16x16x32 MFMA, global_load_lds width-16 staging.
// EPI: 0 = bf16(acc + f32 bias[col])
//      1 = bf16(acc + bf16 aux0[g])              (in-place-safe)
//      2 = bf16(sigmoid(acc) * bf16 aux0[g])     (in-place-safe)
//      3 = f32: outF[g] = acc + f32 auxF[g]
//      4 = bf16(sigmoid(acc))
//      5 = bf16(relu(acc)^2)
//      6 = f32: outF[g] += bf16(aux0[g]) * acc   (read-modify-write)
// ---------------------------------------------------------------------------
template <int EPI>
__global__ __launch_bounds__(256) void gemm_bt(const u16* __restrict__ A,
                                               const u16* __restrict__ B,
                                               u16* outB, float* outF,
                                               const float* __restrict__ biasF,
                                               const u16* aux0,
                                               const float* auxF,
                                               int N, int K, int lda, int ldb) {
    __shared__ u16 As[128 * 64];
    __shared__ u16 Bs[128 * 64];
    int tid = threadIdx.x;
    int lane = tid & 63;
    int wv = tid >> 6;
    int row0 = blockIdx.y * 128;
    int col0 = blockIdx.x * 128;
    int wm = (wv >> 1) * 64;
    int wn = (wv & 1) * 64;
    int frow = lane & 15, quad = lane >> 4;

    float4v zero = {0.f, 0.f, 0.f, 0.f};
    float4v acc[4][4];
#pragma unroll
    for (int i = 0; i < 4; ++i)
#pragma unroll
        for (int j = 0; j < 4; ++j) acc[i][j] = zero;

    for (int k0 = 0; k0 < K; k0 += 64) {
#pragma unroll
        for (int it = 0; it < 4; ++it) {
            int base = (wv * 4 + it) * 512;      // element offset (wave-uniform)
            int e = base + lane * 8;
            int r = e >> 6, c = e & 63;
            GLOAD_LDS16(A + (size_t)(row0 + r) * lda + (k0 + c), &As[base]);
            GLOAD_LDS16(B + (size_t)(col0 + r) * ldb + (k0 + c), &Bs[base]);
        }
        __syncthreads();
#pragma unroll
        for (int kk = 0; kk < 64; kk += 32) {
            short8 a_frag[4], b_frag[4];
#pragma unroll
            for (int mi = 0; mi < 4; ++mi)
                a_frag[mi] = *(const short8*)&As[(wm + mi * 16 + frow) * 64 + kk + quad * 8];
#pragma unroll
            for (int ni = 0; ni < 4; ++ni)
                b_frag[ni] = *(const short8*)&Bs[(wn + ni * 16 + frow) * 64 + kk + quad * 8];
#pragma unroll
            for (int mi = 0; mi < 4; ++mi)
#pragma unroll
                for (int ni = 0; ni < 4; ++ni)
                    acc[mi][ni] = __builtin_amdgcn_mfma_f32_16x16x32_bf16(
                        a_frag[mi], b_frag[ni], acc[mi][ni], 0, 0, 0);
        }
        __syncthreads();
    }

#pragma unroll
    for (int mi = 0; mi < 4; ++mi) {
#pragma unroll
        for (int ni = 0; ni < 4; ++ni) {
#pragma unroll
            for (int r = 0; r < 4; ++r) {
                int row = row0 + wm + mi * 16 + quad * 4 + r;
                int col = col0 + wn + ni * 16 + frow;
                size_t g = (size_t)row * N + col;
                float v = acc[mi][ni][r];
                if constexpr (EPI == 0) {
                    outB[g] = f2b(v + biasF[col]);
                } else if constexpr (EPI == 1) {
                    outB[g] = f2b(v + b2f(aux0[g]));
                } else if constexpr (EPI == 2) {
                    float sg = 1.f / (1.f + expf(-v));
                    outB[g] = f2b(sg * b2f(aux0[g]));
                } else if constexpr (EPI == 3) {
                    outF[g] = v + auxF[g];
                } else if constexpr (EPI == 4) {
                    outB[g] = f2b(1.f / (1.f + expf(-v)));
                } else if constexpr (EPI == 5) {
                    float t = v > 0.f ? v : 0.f;
                    outB[g] = f2b(t * t);
                } else if constexpr (EPI == 6) {
                    outF[g] = outF[g] + b2f(aux0[g]) * v;
                }
            }
        }
    }
}

// ---------------------------------------------------------------------------
extern "C" void kernel_launch(void* const* d_in, const int* in_sizes, int n_in,
                              void* d_out, int out_size, void* d_ws, size_t ws_size,
                              hipStream_t stream) {
    (void)in_sizes; (void)n_in; (void)out_size; (void)ws_size;
    const float* x   = (const float*)d_in[0];
    const float* n1w = (const float*)d_in[1];
    // d_in[2] tm_mix_k, d_in[5] tm_key_w are dead in the reference
    const float* tmv = (const float*)d_in[3];
    const float* tmr = (const float*)d_in[4];
    const float* vw  = (const float*)d_in[6];
    const float* rw  = (const float*)d_in[7];
    const float* ow  = (const float*)d_in[8];
    const float* qw  = (const float*)d_in[9];
    const float* qb  = (const float*)d_in[10];
    const float* skw = (const float*)d_in[11];
    const float* skb = (const float*)d_in[12];
    const float* svw = (const float*)d_in[13];
    const float* svb = (const float*)d_in[14];
    const float* sow = (const float*)d_in[15];
    const float* sob = (const float*)d_in[16];
    const float* n2w = (const float*)d_in[17];
    const float* cmk = (const float*)d_in[18];
    const float* cmr = (const float*)d_in[19];
    const float* ckw = (const float*)d_in[20];
    const float* crw = (const float*)d_in[21];
    const float* cvw = (const float*)d_in[22];

    char* W = (char*)d_ws;
    const size_t MB = 1ull << 20;
    u16*   wsA   = (u16*)(W + 0 * MB);     // 16 MB bf16 activations
    u16*   wsB   = (u16*)(W + 16 * MB);    // 16 MB bf16 activations
    // [32,64) spare (x1 moved into d_out)
    float* Kt4   = (float*)(W + 64 * MB);  // 2 MB f32  [b][g][key][4]
    float* invn  = (float*)(W + 66 * MB);  // 32 KB
    u16*   ckw16 = (u16*)(W + 68 * MB);    // 8 MB
    u16*   cvw16 = (u16*)(W + 76 * MB);    // 8 MB
    u16*   svw16 = (u16*)(W + 84 * MB);    // 2 MB (dead by channel phase)
    u16*   sow16 = (u16*)(W + 86 * MB);
    u16*   vw16  = (u16*)(W + 88 * MB);
    u16*   rw16  = (u16*)(W + 90 * MB);
    u16*   ow16  = (u16*)(W + 92 * MB);
    u16*   chunk = (u16*)(W + 84 * MB);    // 16 MB (channel phase, overlays svw..ow16)
    u16*   crw16 = (u16*)(W + 100 * MB);   // 2 MB
    float* qwT4  = (float*)(W + 102 * MB); // 256 KB -> peak ~102.3 MB
    float* x1    = (float*)d_out;          // 32 MB f32, accumulated in place

    dim3 blk(256);
    dim3 gN1024(8, 64);
    const int NW = 512;

    // weight prep
    wcvt<<<NW, blk, 0, stream>>>(svw, svw16, 1024 * 1024);
    wcvt<<<NW, blk, 0, stream>>>(sow, sow16, 1024 * 1024);
    wcvt<<<NW, blk, 0, stream>>>(vw,  vw16,  1024 * 1024);
    wcvt<<<NW, blk, 0, stream>>>(rw,  rw16,  1024 * 1024);
    wcvt<<<NW, blk, 0, stream>>>(ow,  ow16,  1024 * 1024);
    wcvt<<<NW, blk, 0, stream>>>(crw, crw16, 1024 * 1024);
    wcvt<<<NW, blk, 0, stream>>>(ckw, ckw16, 4096 * 1024);
    wcvt<<<NW, blk, 0, stream>>>(cvw, cvw16, 1024 * 4096);
    prep_qwT4<<<256, blk, 0, stream>>>(qw, qwT4);

    // --- time-mix ---
    kproj<<<8192, blk, 0, stream>>>(x, n1w, skw, skb, Kt4, invn);
    attn_w<<<4096, dim3(128), 0, stream>>>(x, n1w, qwT4, qb, Kt4, invn, wsB);  // y
    // t = y @ sa_v_w^T + svb
    gemm_bt<0><<<gN1024, blk, 0, stream>>>(wsB, svw16, wsA, nullptr, svb, nullptr, nullptr, 1024, 1024, 1024, 1024);
    // attnO = t @ sa_o_w^T + sob
    gemm_bt<0><<<gN1024, blk, 0, stream>>>(wsA, sow16, wsB, nullptr, sob, nullptr, nullptr, 1024, 1024, 1024, 1024);
    // vin
    mix_shift<<<8192, blk, 0, stream>>>(x, n1w, tmv, wsA);
    // z = vin @ tm_value_w^T + attnO   (in-place over attnO in wsB)
    gemm_bt<1><<<gN1024, blk, 0, stream>>>(wsA, vw16, wsB, nullptr, nullptr, wsB, nullptr, 1024, 1024, 1024, 1024);
    // rin
    mix_shift<<<8192, blk, 0, stream>>>(x, n1w, tmr, wsA);
    // rkv = sigmoid(rin @ tm_recept_w^T) * z   (in-place over z in wsB)
    gemm_bt<2><<<gN1024, blk, 0, stream>>>(wsA, rw16, wsB, nullptr, nullptr, wsB, nullptr, 1024, 1024, 1024, 1024);
    // x1 = x + rkv @ tm_out_w^T   (f32, directly into d_out)
    gemm_bt<3><<<gN1024, blk, 0, stream>>>(wsB, ow16, nullptr, x1, nullptr, nullptr, x, 1024, 1024, 1024, 1024);

    // --- channel-mix ---
    mix_shift<<<8192, blk, 0, stream>>>(x1, n2w, cmr, wsA);   // rin2
    gemm_bt<4><<<gN1024, blk, 0, stream>>>(wsA, crw16, wsB, nullptr, nullptr, nullptr, nullptr, 1024, 1024, 1024, 1024);
    mix_shift<<<8192, blk, 0, stream>>>(x1, n2w, cmk, wsA);   // kin2
    for (int c = 0; c < 4; ++c) {
        const u16* ckw_c = ckw16 + (size_t)c * 1024 * 1024;  // rows c*1024..+1024 of (4096,1024)
        const u16* cvw_c = cvw16 + (size_t)c * 1024;         // cols c*1024..+1024 of (1024,4096)
        gemm_bt<5><<<gN1024, blk, 0, stream>>>(wsA, ckw_c, chunk, nullptr, nullptr, nullptr, nullptr,
                                               1024, 1024, 1024, 1024);
        gemm_bt<6><<<gN1024, blk, 0, stream>>>(chunk, cvw_c, nullptr, x1, nullptr, wsB, nullptr,
                                               1024, 1024, 1024, 4096);
    }
}

// Round 7
// 1659.534 us; speedup vs baseline: 1.9916x; 1.0640x over previous
//
#include <hip/hip_runtime.h>
#include <math.h>

typedef unsigned short u16;
using short8  = __attribute__((ext_vector_type(8))) short;
using float4v = __attribute__((ext_vector_type(4))) float;

__device__ __forceinline__ float b2f(u16 u) {
    union { unsigned int i; float f; } v; v.i = ((unsigned int)u) << 16; return v.f;
}
__device__ __forceinline__ u16 f2b(float f) {
    union { float f; unsigned int i; } v; v.f = f;
    unsigned int x = v.i;
    unsigned int r = (x + 0x7fffu + ((x >> 16) & 1u)) >> 16;
    return (u16)r;
}

#define GLOAD_LDS16(gp, lp) \
    __builtin_amdgcn_global_load_lds( \
        (const __attribute__((address_space(1))) unsigned int*)(gp), \
        (__attribute__((address_space(3))) unsigned int*)(lp), 16, 0, 0)

// ---------------------------------------------------------------------------
__global__ __launch_bounds__(256) void wcvt(const float* __restrict__ s,
                                            u16* __restrict__ d, int n) {
    int stride = gridDim.x * 256;
    for (int i = blockIdx.x * 256 + threadIdx.x; i < n; i += stride)
        d[i] = f2b(s[i]);
}

// qw[64][1024] -> qwT4[d>>2][a][d&3]  (lane-coalesced float4 per 4 dims)
__global__ __launch_bounds__(256) void prep_qwT4(const float* __restrict__ qw,
                                                 float* __restrict__ qwT4) {
    int idx = blockIdx.x * 256 + threadIdx.x;   // 65536
    int a = idx >> 10, d = idx & 1023;
    qwT4[(size_t)(d >> 2) * 256 + a * 4 + (d & 3)] = qw[idx];
}

// ---------------------------------------------------------------------------
// mix2out: rmsnorm + token-shift mix, TWO mix coefficients in one pass.
// out1[i,d] = f1[d]*xn_i + (1-f1[d])*xn_{i-1};  out2 same with f2. (bf16)
// ---------------------------------------------------------------------------
__global__ __launch_bounds__(256) void mix2out(const float* __restrict__ src,
                                               const float* __restrict__ w,
                                               const float* __restrict__ f1,
                                               const float* __restrict__ f2,
                                               u16* __restrict__ out1,
                                               u16* __restrict__ out2) {
    __shared__ float redc[256], redp[256];
    int tid = threadIdx.x;
    size_t i = blockIdx.x;
    size_t ip = ((i & 4095) == 0) ? i : i - 1;
    float xc[4], xp[4];
    float ssc = 0.f, ssp = 0.f;
#pragma unroll
    for (int l = 0; l < 4; ++l) {
        int d = tid + l * 256;
        xc[l] = src[i * 1024 + d];  ssc += xc[l] * xc[l];
        xp[l] = src[ip * 1024 + d]; ssp += xp[l] * xp[l];
    }
    redc[tid] = ssc; redp[tid] = ssp; __syncthreads();
    for (int st = 128; st > 0; st >>= 1) {
        if (tid < st) { redc[tid] += redc[tid + st]; redp[tid] += redp[tid + st]; }
        __syncthreads();
    }
    float ic  = 1.f / (sqrtf(redc[0]) * (1.f / 32.f) + 1e-8f);
    float ipv = 1.f / (sqrtf(redp[0]) * (1.f / 32.f) + 1e-8f);
#pragma unroll
    for (int l = 0; l < 4; ++l) {
        int d = tid + l * 256;
        float wd = w[d];
        float xn = wd * xc[l] * ic;
        float xx = wd * xp[l] * ipv;
        float fa = f1[d], fb = f2[d];
        out1[i * 1024 + d] = f2b(fa * xn + (1.f - fa) * xx);
        out2[i * 1024 + d] = f2b(fb * xn + (1.f - fb) * xx);
    }
}

// ---------------------------------------------------------------------------
// kproj (f64 compute, f32 store in transposed Kt4 layout [b][g][key][4]).
// ---------------------------------------------------------------------------
__global__ __launch_bounds__(256) void kproj(const float* __restrict__ x,
                                             const float* __restrict__ w1,
                                             const float* __restrict__ kw,
                                             const float* __restrict__ kb,
                                             float* __restrict__ Kt4,
                                             float* __restrict__ invn) {
    __shared__ double xk[1024];
    __shared__ double red[256];
    int tid = threadIdx.x;
    size_t j = blockIdx.x;
    double ss = 0.0;
    float xc[4];
#pragma unroll
    for (int l = 0; l < 4; ++l) {
        int d = tid + l * 256;
        xc[l] = x[j * 1024 + d];
        ss += (double)xc[l] * (double)xc[l];
    }
    red[tid] = ss; __syncthreads();
    for (int st = 128; st > 0; st >>= 1) {
        if (tid < st) red[tid] += red[tid + st];
        __syncthreads();
    }
    double inv = 1.0 / (sqrt(red[0]) * (1.0 / 32.0) + 1e-8);
#pragma unroll
    for (int l = 0; l < 4; ++l) {
        int d = tid + l * 256;
        xk[d] = (double)w1[d] * (double)xc[l] * inv;
    }
    __syncthreads();
    int wv = tid >> 6, lane = tid & 63;
    int b = (int)(j >> 12), jj = (int)(j & 4095);
    for (int it = 0; it < 16; ++it) {
        int a = wv * 16 + it;
        const float* kr = kw + (size_t)a * 1024;
        double p = 0.0;
#pragma unroll
        for (int m = 0; m < 16; ++m) p += xk[lane + 64 * m] * (double)kr[lane + 64 * m];
        for (int off = 32; off; off >>= 1) p += __shfl_xor(p, off);
        if (lane == 0)
            Kt4[(((size_t)b * 16 + (a >> 2)) * 4096 + jj) * 4 + (a & 3)] = (float)(p + (double)kb[a]);
    }
    if (tid == 0) invn[j] = (float)inv;
}

// ---------------------------------------------------------------------------
// attn_w: one WAVE per query row, zero __syncthreads, double-buffered K
// batches (16+16 float4 in flight) so VMEM latency is amortized 16-deep.
// Selection numerics identical to the round-4/5/6 passing kernels.
// ---------------------------------------------------------------------------
__global__ __launch_bounds__(128, 2) void attn_w(const float* __restrict__ x,
                                                 const float* __restrict__ w1,
                                                 const float* __restrict__ qwT4,
                                                 const float* __restrict__ qb,
                                                 const float* __restrict__ Kt4,
                                                 const float* __restrict__ invn,
                                                 u16* __restrict__ y) {
    __shared__ float  sc[2][4096];
    __shared__ double qv64s[2][64];
    __shared__ int    candL[2][40];
    __shared__ float  pwL[2][32];
    __shared__ int    idxL[2][32];

    int tid = threadIdx.x;
    int w = tid >> 6, lane = tid & 63;
    int i = blockIdx.x * 2 + w;
    int b = i >> 12;
    int base = b << 12;

    // ---- Q projection: lane a computes Q[a]; 4 independent f64 accumulators
    const float* xr = x + (size_t)i * 1024;
    double qp0 = 0.0, qp1 = 0.0, qp2 = 0.0, qp3 = 0.0;
#pragma unroll 4
    for (int d4 = 0; d4 < 256; ++d4) {
        float4 w4  = *(const float4*)(w1 + d4 * 4);
        float4 x4  = *(const float4*)(xr + d4 * 4);
        float4 qw4 = *(const float4*)(qwT4 + (size_t)d4 * 256 + lane * 4);
        qp0 += (double)(w4.x * x4.x) * (double)qw4.x;
        qp1 += (double)(w4.y * x4.y) * (double)qw4.y;
        qp2 += (double)(w4.z * x4.z) * (double)qw4.z;
        qp3 += (double)(w4.w * x4.w) * (double)qw4.w;
    }
    double q = ((qp0 + qp1) + (qp2 + qp3)) * (double)invn[i] + (double)qb[lane];
    qv64s[w][lane] = q;
    float qf = (float)q;

    // broadcast all 64 q values into per-lane registers via shuffles
    float4 qreg[16];
#pragma unroll
    for (int g = 0; g < 16; ++g) {
        qreg[g].x = __shfl(qf, 4 * g + 0);
        qreg[g].y = __shfl(qf, 4 * g + 1);
        qreg[g].z = __shfl(qf, 4 * g + 2);
        qreg[g].w = __shfl(qf, 4 * g + 3);
    }

    // ---- f32 scores, double-buffered 16-wide K batches ----
    const float4* K4 = (const float4*)Kt4 + (size_t)b * 16 * 4096;
    float4 kva[16], kvb[16];
    float lv1 = -3.4e38f, lv2 = -3.4e38f;
    int   li1 = 0x7ffffffe, li2 = 0x7fffffff;
#pragma unroll
    for (int g = 0; g < 16; ++g) kva[g] = K4[g * 4096 + lane];

#define SCORE_PROC(BUF, JEXPR)                                                  \
    {                                                                           \
        int j_ = (JEXPR);                                                       \
        float s_ = 0.f;                                                         \
        _Pragma("unroll")                                                       \
        for (int g = 0; g < 16; ++g)                                            \
            s_ += qreg[g].x * BUF[g].x + qreg[g].y * BUF[g].y                   \
                + qreg[g].z * BUF[g].z + qreg[g].w * BUF[g].w;                  \
        s_ *= 0.125f;                                                           \
        if (!(s_ == s_)) s_ = -3.3e38f;                                         \
        sc[w][j_] = s_;                                                         \
        if (s_ > lv1 || (s_ == lv1 && j_ < li1)) {                              \
            lv2 = lv1; li2 = li1; lv1 = s_; li1 = j_;                           \
        } else if (s_ > lv2 || (s_ == lv2 && j_ < li2)) { lv2 = s_; li2 = j_; } \
    }

#pragma unroll 1
    for (int t = 0; t < 64; t += 2) {
        int j1 = (t + 1) * 64 + lane;
#pragma unroll
        for (int g = 0; g < 16; ++g) kvb[g] = K4[g * 4096 + j1];
        SCORE_PROC(kva, t * 64 + lane);
        if (t + 2 < 64) {
            int j2 = (t + 2) * 64 + lane;
#pragma unroll
            for (int g = 0; g < 16; ++g) kva[g] = K4[g * 4096 + j2];
        }
        SCORE_PROC(kvb, j1);
    }
#undef SCORE_PROC

    // ---- stage-1: extract top-40 (shuffle-only; no barriers) ----
    bool v2ok = true;
    for (int it = 0; it < 40; ++it) {
        float mv = lv1; int mi = li1;
#pragma unroll
        for (int off = 32; off >= 1; off >>= 1) {
            float ov = __shfl_xor(mv, off); int oi = __shfl_xor(mi, off);
            if (ov > mv || (ov == mv && oi < mi)) { mv = ov; mi = oi; }
        }
        if (lane == 0) candL[w][it] = mi;
        if (li1 == mi) {                    // this lane owned the winner
            sc[w][mi] = -3.4e38f;
            if (v2ok) { lv1 = lv2; li1 = li2; v2ok = false; }
            else {                           // rescan own 64 slots, fresh top-2
                lv1 = -3.4e38f; li1 = 0x7ffffffe; lv2 = -3.4e38f; li2 = 0x7fffffff;
                for (int t = 0; t < 64; ++t) {
                    int j = t * 64 + lane;
                    float v = sc[w][j];
                    if (v > lv1 || (v == lv1 && j < li1)) { lv2 = lv1; li2 = li1; lv1 = v; li1 = j; }
                    else if (v > lv2 || (v == lv2 && j < li2)) { lv2 = v; li2 = j; }
                }
                v2ok = true;
            }
        }
    }

    // ---- stage-2: f64 rescore of the 40 candidates ----
    int c = (lane < 40) ? lane : 0;
    int j = candL[w][c];
    double s = 0.0;
#pragma unroll
    for (int g = 0; g < 16; ++g) {
        float4 kv = K4[g * 4096 + j];
        s += qv64s[w][4 * g + 0] * (double)kv.x + qv64s[w][4 * g + 1] * (double)kv.y
           + qv64s[w][4 * g + 2] * (double)kv.z + qv64s[w][4 * g + 3] * (double)kv.w;
    }
    s *= 0.125;
    if (lane >= 40) { s = -1.0e300; j = 0x7fffffff; }

    // ---- exact rank among the 40 (tie -> lower key index) ----
    int rank = 0;
    for (int c2 = 0; c2 < 40; ++c2) {
        double s2 = __shfl(s, c2); int j2 = __shfl(j, c2);
        if (s2 > s || (s2 == s && j2 < j)) ++rank;
    }

    // ---- f64 softmax over ranks 0..31 ----
    unsigned long long m0 = __ballot(rank == 0);
    int src = __ffsll((unsigned long long)m0) - 1;
    double mx = __shfl(s, src);
    double e = (rank < 32) ? exp(s - mx) : 0.0;
    double sum = e;
#pragma unroll
    for (int off = 1; off < 64; off <<= 1) sum += __shfl_xor(sum, off);
    if (rank < 32) {
        pwL[w][rank] = (float)(e / sum) * invn[base + j];
        idxL[w][rank] = j;
    }

    // ---- gather (double-buffered rows): y = w1 .* sum_k p_k * x_row(k) ----
    float acc[16], xga[16], xgb[16];
#pragma unroll
    for (int m = 0; m < 16; ++m) acc[m] = 0.f;
    {
        const float* x0 = x + (size_t)(base + idxL[w][0]) * 1024;
#pragma unroll
        for (int m = 0; m < 16; ++m) xga[m] = x0[m * 64 + lane];
    }
#pragma unroll 1
    for (int k = 0; k < 32; k += 2) {
        const float* xn1 = x + (size_t)(base + idxL[w][k + 1]) * 1024;
#pragma unroll
        for (int m = 0; m < 16; ++m) xgb[m] = xn1[m * 64 + lane];
        float p0 = pwL[w][k];
#pragma unroll
        for (int m = 0; m < 16; ++m) acc[m] += p0 * xga[m];
        if (k + 2 < 32) {
            const float* xn2 = x + (size_t)(base + idxL[w][k + 2]) * 1024;
#pragma unroll
            for (int m = 0; m < 16; ++m) xga[m] = xn2[m * 64 + lane];
        }
        float p1 = pwL[w][k + 1];
#pragma unroll
        for (int m = 0; m < 16; ++m) acc[m] += p1 * xgb[m];
    }
#pragma unroll
    for (int m = 0; m < 16; ++m) {
        int d = m * 64 + lane;
        y[(size_t)i * 1024 + d] = f2b(w1[d] * acc[m]);
    }
}

// ---------------------------------------------------------------------------
// MFMA bf16 GEMM: C[M,N] = A[M,K] @ B[N,K]^T. 128x128 tile, BK=64,
// 4 waves (2x2 of 64x64), 16x16x32 MFMA, global_load_lds width-16 staging.
// EPI: 0 = bf16(acc + f32 bias[col])
//      1 = bf16(acc + bf16 aux0[g])              (in-place-safe)
//      2 = bf16(sigmoid(acc) * bf16 aux0[g])     (in-place-safe)
//      3 = f32: outF[g] = acc + f32 auxF[g]
//      4 = bf16(sigmoid(acc))
//      5 = bf16(relu(acc)^2)
//      6 = f32: outF[g] += bf16(aux0[g]) * acc   (read-modify-write)
// ---------------------------------------------------------------------------
template <int EPI>
__global__ __launch_bounds__(256) void gemm_bt(const u16* __restrict__ A,
                                               const u16* __restrict__ B,
                                               u16* outB, float* outF,
                                               const float* __restrict__ biasF,
                                               const u16* aux0,
                                               const float* auxF,
                                               int N, int K, int lda, int ldb) {
    __shared__ u16 As[128 * 64];
    __shared__ u16 Bs[128 * 64];
    int tid = threadIdx.x;
    int lane = tid & 63;
    int wv = tid >> 6;
    int row0 = blockIdx.y * 128;
    int col0 = blockIdx.x * 128;
    int wm = (wv >> 1) * 64;
    int wn = (wv & 1) * 64;
    int frow = lane & 15, quad = lane >> 4;

    float4v zero = {0.f, 0.f, 0.f, 0.f};
    float4v acc[4][4];
#pragma unroll
    for (int i = 0; i < 4; ++i)
#pragma unroll
        for (int j = 0; j < 4; ++j) acc[i][j] = zero;

    for (int k0 = 0; k0 < K; k0 += 64) {
#pragma unroll
        for (int it = 0; it < 4; ++it) {
            int base = (wv * 4 + it) * 512;      // element offset (wave-uniform)
            int e = base + lane * 8;
            int r = e >> 6, c = e & 63;
            GLOAD_LDS16(A + (size_t)(row0 + r) * lda + (k0 + c), &As[base]);
            GLOAD_LDS16(B + (size_t)(col0 + r) * ldb + (k0 + c), &Bs[base]);
        }
        __syncthreads();
#pragma unroll
        for (int kk = 0; kk < 64; kk += 32) {
            short8 a_frag[4], b_frag[4];
#pragma unroll
            for (int mi = 0; mi < 4; ++mi)
                a_frag[mi] = *(const short8*)&As[(wm + mi * 16 + frow) * 64 + kk + quad * 8];
#pragma unroll
            for (int ni = 0; ni < 4; ++ni)
                b_frag[ni] = *(const short8*)&Bs[(wn + ni * 16 + frow) * 64 + kk + quad * 8];
#pragma unroll
            for (int mi = 0; mi < 4; ++mi)
#pragma unroll
                for (int ni = 0; ni < 4; ++ni)
                    acc[mi][ni] = __builtin_amdgcn_mfma_f32_16x16x32_bf16(
                        a_frag[mi], b_frag[ni], acc[mi][ni], 0, 0, 0);
        }
        __syncthreads();
    }

#pragma unroll
    for (int mi = 0; mi < 4; ++mi) {
#pragma unroll
        for (int ni = 0; ni < 4; ++ni) {
#pragma unroll
            for (int r = 0; r < 4; ++r) {
                int row = row0 + wm + mi * 16 + quad * 4 + r;
                int col = col0 + wn + ni * 16 + frow;
                size_t g = (size_t)row * N + col;
                float v = acc[mi][ni][r];
                if constexpr (EPI == 0) {
                    outB[g] = f2b(v + biasF[col]);
                } else if constexpr (EPI == 1) {
                    outB[g] = f2b(v + b2f(aux0[g]));
                } else if constexpr (EPI == 2) {
                    float sg = 1.f / (1.f + expf(-v));
                    outB[g] = f2b(sg * b2f(aux0[g]));
                } else if constexpr (EPI == 3) {
                    outF[g] = v + auxF[g];
                } else if constexpr (EPI == 4) {
                    outB[g] = f2b(1.f / (1.f + expf(-v)));
                } else if constexpr (EPI == 5) {
                    float t = v > 0.f ? v : 0.f;
                    outB[g] = f2b(t * t);
                } else if constexpr (EPI == 6) {
                    outF[g] = outF[g] + b2f(aux0[g]) * v;
                }
            }
        }
    }
}

// ---------------------------------------------------------------------------
extern "C" void kernel_launch(void* const* d_in, const int* in_sizes, int n_in,
                              void* d_out, int out_size, void* d_ws, size_t ws_size,
                              hipStream_t stream) {
    (void)in_sizes; (void)n_in; (void)out_size; (void)ws_size;
    const float* x   = (const float*)d_in[0];
    const float* n1w = (const float*)d_in[1];
    // d_in[2] tm_mix_k, d_in[5] tm_key_w are dead in the reference
    const float* tmv = (const float*)d_in[3];
    const float* tmr = (const float*)d_in[4];
    const float* vw  = (const float*)d_in[6];
    const float* rw  = (const float*)d_in[7];
    const float* ow  = (const float*)d_in[8];
    const float* qw  = (const float*)d_in[9];
    const float* qb  = (const float*)d_in[10];
    const float* skw = (const float*)d_in[11];
    const float* skb = (const float*)d_in[12];
    const float* svw = (const float*)d_in[13];
    const float* svb = (const float*)d_in[14];
    const float* sow = (const float*)d_in[15];
    const float* sob = (const float*)d_in[16];
    const float* n2w = (const float*)d_in[17];
    const float* cmk = (const float*)d_in[18];
    const float* cmr = (const float*)d_in[19];
    const float* ckw = (const float*)d_in[20];
    const float* crw = (const float*)d_in[21];
    const float* cvw = (const float*)d_in[22];

    char* W = (char*)d_ws;
    const size_t MB = 1ull << 20;
    u16*   bufA  = (u16*)(W + 0 * MB);     // 16 MB
    u16*   bufB  = (u16*)(W + 16 * MB);    // 16 MB (with C forms 32 MB k2 chunk)
    u16*   bufC  = (u16*)(W + 32 * MB);    // 16 MB
    u16*   bufD  = (u16*)(W + 48 * MB);    // 16 MB
    float* Kt4   = (float*)(W + 64 * MB);  // 2 MB  [b][g][key][4]
    float* invn  = (float*)(W + 66 * MB);  // 32 KB
    float* qwT4  = (float*)(W + 67 * MB);  // 256 KB
    u16*   ckw16 = (u16*)(W + 68 * MB);    // 8 MB
    u16*   cvw16 = (u16*)(W + 76 * MB);    // 8 MB
    u16*   svw16 = (u16*)(W + 84 * MB);    // 2 MB each below
    u16*   sow16 = (u16*)(W + 86 * MB);
    u16*   vw16  = (u16*)(W + 88 * MB);
    u16*   rw16  = (u16*)(W + 90 * MB);
    u16*   ow16  = (u16*)(W + 92 * MB);
    u16*   crw16 = (u16*)(W + 94 * MB);    // peak 96 MB (< proven 102.3 MB)
    float* x1    = (float*)d_out;          // 32 MB f32, accumulated in place

    dim3 blk(256);
    dim3 gN1024(8, 64);
    dim3 gN2048(16, 64);
    const int NW = 512;

    // weight prep
    wcvt<<<NW, blk, 0, stream>>>(svw, svw16, 1024 * 1024);
    wcvt<<<NW, blk, 0, stream>>>(sow, sow16, 1024 * 1024);
    wcvt<<<NW, blk, 0, stream>>>(vw,  vw16,  1024 * 1024);
    wcvt<<<NW, blk, 0, stream>>>(rw,  rw16,  1024 * 1024);
    wcvt<<<NW, blk, 0, stream>>>(ow,  ow16,  1024 * 1024);
    wcvt<<<NW, blk, 0, stream>>>(crw, crw16, 1024 * 1024);
    wcvt<<<NW, blk, 0, stream>>>(ckw, ckw16, 4096 * 1024);
    wcvt<<<NW, blk, 0, stream>>>(cvw, cvw16, 1024 * 4096);
    prep_qwT4<<<256, blk, 0, stream>>>(qw, qwT4);

    // --- time-mix ---
    mix2out<<<8192, blk, 0, stream>>>(x, n1w, tmv, tmr, bufA, bufC);  // vin, rin
    kproj<<<8192, blk, 0, stream>>>(x, n1w, skw, skb, Kt4, invn);
    attn_w<<<4096, dim3(128), 0, stream>>>(x, n1w, qwT4, qb, Kt4, invn, bufB); // y
    // t = y @ sa_v_w^T + svb
    gemm_bt<0><<<gN1024, blk, 0, stream>>>(bufB, svw16, bufD, nullptr, svb, nullptr, nullptr, 1024, 1024, 1024, 1024);
    // attnO = t @ sa_o_w^T + sob  (overwrites y, dead)
    gemm_bt<0><<<gN1024, blk, 0, stream>>>(bufD, sow16, bufB, nullptr, sob, nullptr, nullptr, 1024, 1024, 1024, 1024);
    // z = vin @ tm_value_w^T + attnO   (in-place over attnO)
    gemm_bt<1><<<gN1024, blk, 0, stream>>>(bufA, vw16, bufB, nullptr, nullptr, bufB, nullptr, 1024, 1024, 1024, 1024);
    // rkv = sigmoid(rin @ tm_recept_w^T) * z   (in-place over z)
    gemm_bt<2><<<gN1024, blk, 0, stream>>>(bufC, rw16, bufB, nullptr, nullptr, bufB, nullptr, 1024, 1024, 1024, 1024);
    // x1 = x + rkv @ tm_out_w^T   (f32, into d_out)
    gemm_bt<3><<<gN1024, blk, 0, stream>>>(bufB, ow16, nullptr, x1, nullptr, nullptr, x, 1024, 1024, 1024, 1024);

    // --- channel-mix ---
    mix2out<<<8192, blk, 0, stream>>>(x1, n2w, cmk, cmr, bufA, bufC);  // kin2, rin2
    // sig2 = sigmoid(rin2 @ cm_recept_w^T) -> D
    gemm_bt<4><<<gN1024, blk, 0, stream>>>(bufC, crw16, bufD, nullptr, nullptr, nullptr, nullptr, 1024, 1024, 1024, 1024);
    // 2 chunks of 2048 DI-columns; k2 chunk (32 MB bf16) spans bufB..bufC
    for (int c = 0; c < 2; ++c) {
        const u16* ckw_c = ckw16 + (size_t)c * 2048 * 1024;  // rows c*2048.. of (4096,1024)
        const u16* cvw_c = cvw16 + (size_t)c * 2048;         // cols c*2048.. of (1024,4096)
        gemm_bt<5><<<gN2048, blk, 0, stream>>>(bufA, ckw_c, bufB, nullptr, nullptr, nullptr, nullptr,
                                               2048, 1024, 1024, 1024);
        gemm_bt<6><<<gN1024, blk, 0, stream>>>(bufB, cvw_c, nullptr, x1, nullptr, bufD, nullptr,
                                               1024, 2048, 2048, 4096);
    }
}

// Round 8
// 1536.991 us; speedup vs baseline: 2.1504x; 1.0797x over previous
//
#include <hip/hip_runtime.h>
#include <math.h>

typedef unsigned short u16;
using short8  = __attribute__((ext_vector_type(8))) short;
using float4v = __attribute__((ext_vector_type(4))) float;

__device__ __forceinline__ float b2f(u16 u) {
    union { unsigned int i; float f; } v; v.i = ((unsigned int)u) << 16; return v.f;
}
__device__ __forceinline__ u16 f2b(float f) {
    union { float f; unsigned int i; } v; v.f = f;
    unsigned int x = v.i;
    unsigned int r = (x + 0x7fffu + ((x >> 16) & 1u)) >> 16;
    return (u16)r;
}

#define GLOAD_LDS16(gp, lp) \
    __builtin_amdgcn_global_load_lds( \
        (const __attribute__((address_space(1))) unsigned int*)(gp), \
        (__attribute__((address_space(3))) unsigned int*)(lp), 16, 0, 0)

// ---------------------------------------------------------------------------
__global__ __launch_bounds__(256) void wcvt(const float* __restrict__ s,
                                            u16* __restrict__ d, int n) {
    int stride = gridDim.x * 256;
    for (int i = blockIdx.x * 256 + threadIdx.x; i < n; i += stride)
        d[i] = f2b(s[i]);
}

// qw[64][1024] -> qwT4[d>>2][a][d&3]  (lane-coalesced float4 per 4 dims)
__global__ __launch_bounds__(256) void prep_qwT4(const float* __restrict__ qw,
                                                 float* __restrict__ qwT4) {
    int idx = blockIdx.x * 256 + threadIdx.x;   // 65536
    int a = idx >> 10, d = idx & 1023;
    qwT4[(size_t)(d >> 2) * 256 + a * 4 + (d & 3)] = qw[idx];
}

// ---------------------------------------------------------------------------
// mix2out: rmsnorm + token-shift mix, TWO mix coefficients in one pass.
// ---------------------------------------------------------------------------
__global__ __launch_bounds__(256) void mix2out(const float* __restrict__ src,
                                               const float* __restrict__ w,
                                               const float* __restrict__ f1,
                                               const float* __restrict__ f2,
                                               u16* __restrict__ out1,
                                               u16* __restrict__ out2) {
    __shared__ float redc[256], redp[256];
    int tid = threadIdx.x;
    size_t i = blockIdx.x;
    size_t ip = ((i & 4095) == 0) ? i : i - 1;
    float xc[4], xp[4];
    float ssc = 0.f, ssp = 0.f;
#pragma unroll
    for (int l = 0; l < 4; ++l) {
        int d = tid + l * 256;
        xc[l] = src[i * 1024 + d];  ssc += xc[l] * xc[l];
        xp[l] = src[ip * 1024 + d]; ssp += xp[l] * xp[l];
    }
    redc[tid] = ssc; redp[tid] = ssp; __syncthreads();
    for (int st = 128; st > 0; st >>= 1) {
        if (tid < st) { redc[tid] += redc[tid + st]; redp[tid] += redp[tid + st]; }
        __syncthreads();
    }
    float ic  = 1.f / (sqrtf(redc[0]) * (1.f / 32.f) + 1e-8f);
    float ipv = 1.f / (sqrtf(redp[0]) * (1.f / 32.f) + 1e-8f);
#pragma unroll
    for (int l = 0; l < 4; ++l) {
        int d = tid + l * 256;
        float wd = w[d];
        float xn = wd * xc[l] * ic;
        float xx = wd * xp[l] * ipv;
        float fa = f1[d], fb = f2[d];
        out1[i * 1024 + d] = f2b(fa * xn + (1.f - fa) * xx);
        out2[i * 1024 + d] = f2b(fb * xn + (1.f - fb) * xx);
    }
}

// ---------------------------------------------------------------------------
// kproj (f64 compute, f32 store in transposed Kt4 layout [b][g][key][4]).
// ---------------------------------------------------------------------------
__global__ __launch_bounds__(256) void kproj(const float* __restrict__ x,
                                             const float* __restrict__ w1,
                                             const float* __restrict__ kw,
                                             const float* __restrict__ kb,
                                             float* __restrict__ Kt4,
                                             float* __restrict__ invn) {
    __shared__ double xk[1024];
    __shared__ double red[256];
    int tid = threadIdx.x;
    size_t j = blockIdx.x;
    double ss = 0.0;
    float xc[4];
#pragma unroll
    for (int l = 0; l < 4; ++l) {
        int d = tid + l * 256;
        xc[l] = x[j * 1024 + d];
        ss += (double)xc[l] * (double)xc[l];
    }
    red[tid] = ss; __syncthreads();
    for (int st = 128; st > 0; st >>= 1) {
        if (tid < st) red[tid] += red[tid + st];
        __syncthreads();
    }
    double inv = 1.0 / (sqrt(red[0]) * (1.0 / 32.0) + 1e-8);
#pragma unroll
    for (int l = 0; l < 4; ++l) {
        int d = tid + l * 256;
        xk[d] = (double)w1[d] * (double)xc[l] * inv;
    }
    __syncthreads();
    int wv = tid >> 6, lane = tid & 63;
    int b = (int)(j >> 12), jj = (int)(j & 4095);
    for (int it = 0; it < 16; ++it) {
        int a = wv * 16 + it;
        const float* kr = kw + (size_t)a * 1024;
        double p = 0.0;
#pragma unroll
        for (int m = 0; m < 16; ++m) p += xk[lane + 64 * m] * (double)kr[lane + 64 * m];
        for (int off = 32; off; off >>= 1) p += __shfl_xor(p, off);
        if (lane == 0)
            Kt4[(((size_t)b * 16 + (a >> 2)) * 4096 + jj) * 4 + (a & 3)] = (float)(p + (double)kb[a]);
    }
    if (tid == 0) invn[j] = (float)inv;
}

// ---------------------------------------------------------------------------
// attn_w: ONE WAVE = ONE BLOCK = one query row. 64-thread blocks with
// __launch_bounds__(64,1) -> VGPR cap 512: the K double-buffer (128 VGPRs)
// + qreg (64) stay in registers (round-7's 112-VGPR build spilled them to
// scratch -> 474 MB scratch traffic -> latency death). Zero __syncthreads.
// Selection numerics identical to rounds 4-7 (all passing).
// ---------------------------------------------------------------------------
__global__ __launch_bounds__(64, 1) void attn_w(const float* __restrict__ x,
                                                const float* __restrict__ w1,
                                                const float* __restrict__ qwT4,
                                                const float* __restrict__ qb,
                                                const float* __restrict__ Kt4,
                                                const float* __restrict__ invn,
                                                u16* __restrict__ y) {
    __shared__ float  sc[4096];
    __shared__ double qv64s[64];
    __shared__ int    candL[40];
    __shared__ float  pwL[32];
    __shared__ int    idxL[32];

    int lane = threadIdx.x;
    int i = blockIdx.x;
    int b = i >> 12;
    int base = b << 12;

    // ---- Q projection: lane a computes Q[a]; 4 independent f64 accumulators
    const float* xr = x + (size_t)i * 1024;
    double qp0 = 0.0, qp1 = 0.0, qp2 = 0.0, qp3 = 0.0;
#pragma unroll 4
    for (int d4 = 0; d4 < 256; ++d4) {
        float4 w4  = *(const float4*)(w1 + d4 * 4);
        float4 x4  = *(const float4*)(xr + d4 * 4);
        float4 qw4 = *(const float4*)(qwT4 + (size_t)d4 * 256 + lane * 4);
        qp0 += (double)(w4.x * x4.x) * (double)qw4.x;
        qp1 += (double)(w4.y * x4.y) * (double)qw4.y;
        qp2 += (double)(w4.z * x4.z) * (double)qw4.z;
        qp3 += (double)(w4.w * x4.w) * (double)qw4.w;
    }
    double q = ((qp0 + qp1) + (qp2 + qp3)) * (double)invn[i] + (double)qb[lane];
    qv64s[lane] = q;
    float qf = (float)q;

    // broadcast all 64 q values into per-lane registers via shuffles
    float4 qreg[16];
#pragma unroll
    for (int g = 0; g < 16; ++g) {
        qreg[g].x = __shfl(qf, 4 * g + 0);
        qreg[g].y = __shfl(qf, 4 * g + 1);
        qreg[g].z = __shfl(qf, 4 * g + 2);
        qreg[g].w = __shfl(qf, 4 * g + 3);
    }

    // ---- f32 scores, double-buffered 16-wide K batches ----
    const float4* K4 = (const float4*)Kt4 + (size_t)b * 16 * 4096;
    float4 kva[16], kvb[16];
    float lv1 = -3.4e38f, lv2 = -3.4e38f;
    int   li1 = 0x7ffffffe, li2 = 0x7fffffff;
#pragma unroll
    for (int g = 0; g < 16; ++g) kva[g] = K4[g * 4096 + lane];

#define SCORE_PROC(BUF, JEXPR)                                                  \
    {                                                                           \
        int j_ = (JEXPR);                                                       \
        float s_ = 0.f;                                                         \
        _Pragma("unroll")                                                       \
        for (int g = 0; g < 16; ++g)                                            \
            s_ += qreg[g].x * BUF[g].x + qreg[g].y * BUF[g].y                   \
                + qreg[g].z * BUF[g].z + qreg[g].w * BUF[g].w;                  \
        s_ *= 0.125f;                                                           \
        if (!(s_ == s_)) s_ = -3.3e38f;                                         \
        sc[j_] = s_;                                                            \
        if (s_ > lv1 || (s_ == lv1 && j_ < li1)) {                              \
            lv2 = lv1; li2 = li1; lv1 = s_; li1 = j_;                           \
        } else if (s_ > lv2 || (s_ == lv2 && j_ < li2)) { lv2 = s_; li2 = j_; } \
    }

#pragma unroll 1
    for (int t = 0; t < 64; t += 2) {
        int j1 = (t + 1) * 64 + lane;
#pragma unroll
        for (int g = 0; g < 16; ++g) kvb[g] = K4[g * 4096 + j1];
        SCORE_PROC(kva, t * 64 + lane);
        if (t + 2 < 64) {
            int j2 = (t + 2) * 64 + lane;
#pragma unroll
            for (int g = 0; g < 16; ++g) kva[g] = K4[g * 4096 + j2];
        }
        SCORE_PROC(kvb, j1);
    }
#undef SCORE_PROC

    // ---- stage-1: extract top-40 (shuffle-only; no barriers) ----
    bool v2ok = true;
    for (int it = 0; it < 40; ++it) {
        float mv = lv1; int mi = li1;
#pragma unroll
        for (int off = 32; off >= 1; off >>= 1) {
            float ov = __shfl_xor(mv, off); int oi = __shfl_xor(mi, off);
            if (ov > mv || (ov == mv && oi < mi)) { mv = ov; mi = oi; }
        }
        if (lane == 0) candL[it] = mi;
        if (li1 == mi) {                    // this lane owned the winner
            sc[mi] = -3.4e38f;
            if (v2ok) { lv1 = lv2; li1 = li2; v2ok = false; }
            else {                           // rescan own 64 slots, fresh top-2
                lv1 = -3.4e38f; li1 = 0x7ffffffe; lv2 = -3.4e38f; li2 = 0x7fffffff;
                for (int t = 0; t < 64; ++t) {
                    int j = t * 64 + lane;
                    float v = sc[j];
                    if (v > lv1 || (v == lv1 && j < li1)) { lv2 = lv1; li2 = li1; lv1 = v; li1 = j; }
                    else if (v > lv2 || (v == lv2 && j < li2)) { lv2 = v; li2 = j; }
                }
                v2ok = true;
            }
        }
    }

    // ---- stage-2: f64 rescore of the 40 candidates ----
    int c = (lane < 40) ? lane : 0;
    int j = candL[c];
    double s = 0.0;
#pragma unroll
    for (int g = 0; g < 16; ++g) {
        float4 kv = K4[g * 4096 + j];
        s += qv64s[4 * g + 0] * (double)kv.x + qv64s[4 * g + 1] * (double)kv.y
           + qv64s[4 * g + 2] * (double)kv.z + qv64s[4 * g + 3] * (double)kv.w;
    }
    s *= 0.125;
    if (lane >= 40) { s = -1.0e300; j = 0x7fffffff; }

    // ---- exact rank among the 40 (tie -> lower key index) ----
    int rank = 0;
    for (int c2 = 0; c2 < 40; ++c2) {
        double s2 = __shfl(s, c2); int j2 = __shfl(j, c2);
        if (s2 > s || (s2 == s && j2 < j)) ++rank;
    }

    // ---- f64 softmax over ranks 0..31 ----
    unsigned long long m0 = __ballot(rank == 0);
    int src = __ffsll((unsigned long long)m0) - 1;
    double mx = __shfl(s, src);
    double e = (rank < 32) ? exp(s - mx) : 0.0;
    double sum = e;
#pragma unroll
    for (int off = 1; off < 64; off <<= 1) sum += __shfl_xor(sum, off);
    if (rank < 32) {
        pwL[rank] = (float)(e / sum) * invn[base + j];
        idxL[rank] = j;
    }

    // ---- gather (double-buffered rows): y = w1 .* sum_k p_k * x_row(k) ----
    float acc[16], xga[16], xgb[16];
#pragma unroll
    for (int m = 0; m < 16; ++m) acc[m] = 0.f;
    {
        const float* x0 = x + (size_t)(base + idxL[0]) * 1024;
#pragma unroll
        for (int m = 0; m < 16; ++m) xga[m] = x0[m * 64 + lane];
    }
#pragma unroll 1
    for (int k = 0; k < 32; k += 2) {
        const float* xn1 = x + (size_t)(base + idxL[k + 1]) * 1024;
#pragma unroll
        for (int m = 0; m < 16; ++m) xgb[m] = xn1[m * 64 + lane];
        float p0 = pwL[k];
#pragma unroll
        for (int m = 0; m < 16; ++m) acc[m] += p0 * xga[m];
        if (k + 2 < 32) {
            const float* xn2 = x + (size_t)(base + idxL[k + 2]) * 1024;
#pragma unroll
            for (int m = 0; m < 16; ++m) xga[m] = xn2[m * 64 + lane];
        }
        float p1 = pwL[k + 1];
#pragma unroll
        for (int m = 0; m < 16; ++m) acc[m] += p1 * xgb[m];
    }
#pragma unroll
    for (int m = 0; m < 16; ++m) {
        int d = m * 64 + lane;
        y[(size_t)i * 1024 + d] = f2b(w1[d] * acc[m]);
    }
}

// ---------------------------------------------------------------------------
// MFMA bf16 GEMM: C[M,N] = A[M,K] @ B[N,K]^T. 128x128 tile, BK=64,
// 4 waves (2x2 of 64x64), 16x16x32 MFMA, global_load_lds width-16 staging.
// EPI: 0 = bf16(acc + f32 bias[col])
//      1 = bf16(acc + bf16 aux0[g])              (in-place-safe)
//      2 = bf16(sigmoid(acc) * bf16 aux0[g])     (in-place-safe)
//      3 = f32: outF[g] = acc + f32 auxF[g]
//      4 = bf16(sigmoid(acc))
//      5 = bf16(relu(acc)^2)
//      6 = f32: outF[g] += bf16(aux0[g]) * acc   (read-modify-write)
// ---------------------------------------------------------------------------
template <int EPI>
__global__ __launch_bounds__(256) void gemm_bt(const u16* __restrict__ A,
                                               const u16* __restrict__ B,
                                               u16* outB, float* outF,
                                               const float* __restrict__ biasF,
                                               const u16* aux0,
                                               const float* auxF,
                                               int N, int K, int lda, int ldb) {
    __shared__ u16 As[128 * 64];
    __shared__ u16 Bs[128 * 64];
    int tid = threadIdx.x;
    int lane = tid & 63;
    int wv = tid >> 6;
    int row0 = blockIdx.y * 128;
    int col0 = blockIdx.x * 128;
    int wm = (wv >> 1) * 64;
    int wn = (wv & 1) * 64;
    int frow = lane & 15, quad = lane >> 4;

    float4v zero = {0.f, 0.f, 0.f, 0.f};
    float4v acc[4][4];
#pragma unroll
    for (int i = 0; i < 4; ++i)
#pragma unroll
        for (int j = 0; j < 4; ++j) acc[i][j] = zero;

    for (int k0 = 0; k0 < K; k0 += 64) {
#pragma unroll
        for (int it = 0; it < 4; ++it) {
            int base = (wv * 4 + it) * 512;      // element offset (wave-uniform)
            int e = base + lane * 8;
            int r = e >> 6, c = e & 63;
            GLOAD_LDS16(A + (size_t)(row0 + r) * lda + (k0 + c), &As[base]);
            GLOAD_LDS16(B + (size_t)(col0 + r) * ldb + (k0 + c), &Bs[base]);
        }
        __syncthreads();
#pragma unroll
        for (int kk = 0; kk < 64; kk += 32) {
            short8 a_frag[4], b_frag[4];
#pragma unroll
            for (int mi = 0; mi < 4; ++mi)
                a_frag[mi] = *(const short8*)&As[(wm + mi * 16 + frow) * 64 + kk + quad * 8];
#pragma unroll
            for (int ni = 0; ni < 4; ++ni)
                b_frag[ni] = *(const short8*)&Bs[(wn + ni * 16 + frow) * 64 + kk + quad * 8];
#pragma unroll
            for (int mi = 0; mi < 4; ++mi)
#pragma unroll
                for (int ni = 0; ni < 4; ++ni)
                    acc[mi][ni] = __builtin_amdgcn_mfma_f32_16x16x32_bf16(
                        a_frag[mi], b_frag[ni], acc[mi][ni], 0, 0, 0);
        }
        __syncthreads();
    }

#pragma unroll
    for (int mi = 0; mi < 4; ++mi) {
#pragma unroll
        for (int ni = 0; ni < 4; ++ni) {
#pragma unroll
            for (int r = 0; r < 4; ++r) {
                int row = row0 + wm + mi * 16 + quad * 4 + r;
                int col = col0 + wn + ni * 16 + frow;
                size_t g = (size_t)row * N + col;
                float v = acc[mi][ni][r];
                if constexpr (EPI == 0) {
                    outB[g] = f2b(v + biasF[col]);
                } else if constexpr (EPI == 1) {
                    outB[g] = f2b(v + b2f(aux0[g]));
                } else if constexpr (EPI == 2) {
                    float sg = 1.f / (1.f + expf(-v));
                    outB[g] = f2b(sg * b2f(aux0[g]));
                } else if constexpr (EPI == 3) {
                    outF[g] = v + auxF[g];
                } else if constexpr (EPI == 4) {
                    outB[g] = f2b(1.f / (1.f + expf(-v)));
                } else if constexpr (EPI == 5) {
                    float t = v > 0.f ? v : 0.f;
                    outB[g] = f2b(t * t);
                } else if constexpr (EPI == 6) {
                    outF[g] = outF[g] + b2f(aux0[g]) * v;
                }
            }
        }
    }
}

// ---------------------------------------------------------------------------
extern "C" void kernel_launch(void* const* d_in, const int* in_sizes, int n_in,
                              void* d_out, int out_size, void* d_ws, size_t ws_size,
                              hipStream_t stream) {
    (void)in_sizes; (void)n_in; (void)out_size; (void)ws_size;
    const float* x   = (const float*)d_in[0];
    const float* n1w = (const float*)d_in[1];
    // d_in[2] tm_mix_k, d_in[5] tm_key_w are dead in the reference
    const float* tmv = (const float*)d_in[3];
    const float* tmr = (const float*)d_in[4];
    const float* vw  = (const float*)d_in[6];
    const float* rw  = (const float*)d_in[7];
    const float* ow  = (const float*)d_in[8];
    const float* qw  = (const float*)d_in[9];
    const float* qb  = (const float*)d_in[10];
    const float* skw = (const float*)d_in[11];
    const float* skb = (const float*)d_in[12];
    const float* svw = (const float*)d_in[13];
    const float* svb = (const float*)d_in[14];
    const float* sow = (const float*)d_in[15];
    const float* sob = (const float*)d_in[16];
    const float* n2w = (const float*)d_in[17];
    const float* cmk = (const float*)d_in[18];
    const float* cmr = (const float*)d_in[19];
    const float* ckw = (const float*)d_in[20];
    const float* crw = (const float*)d_in[21];
    const float* cvw = (const float*)d_in[22];

    char* W = (char*)d_ws;
    const size_t MB = 1ull << 20;
    u16*   bufA  = (u16*)(W + 0 * MB);     // 16 MB
    u16*   bufB  = (u16*)(W + 16 * MB);    // 16 MB (with C forms 32 MB k2 chunk)
    u16*   bufC  = (u16*)(W + 32 * MB);    // 16 MB
    u16*   bufD  = (u16*)(W + 48 * MB);    // 16 MB
    float* Kt4   = (float*)(W + 64 * MB);  // 2 MB  [b][g][key][4]
    float* invn  = (float*)(W + 66 * MB);  // 32 KB
    float* qwT4  = (float*)(W + 67 * MB);  // 256 KB
    u16*   ckw16 = (u16*)(W + 68 * MB);    // 8 MB
    u16*   cvw16 = (u16*)(W + 76 * MB);    // 8 MB
    u16*   svw16 = (u16*)(W + 84 * MB);    // 2 MB each below
    u16*   sow16 = (u16*)(W + 86 * MB);
    u16*   vw16  = (u16*)(W + 88 * MB);
    u16*   rw16  = (u16*)(W + 90 * MB);
    u16*   ow16  = (u16*)(W + 92 * MB);
    u16*   crw16 = (u16*)(W + 94 * MB);    // peak 96 MB
    float* x1    = (float*)d_out;          // 32 MB f32, accumulated in place

    dim3 blk(256);
    dim3 gN1024(8, 64);
    dim3 gN2048(16, 64);
    const int NW = 512;

    // weight prep
    wcvt<<<NW, blk, 0, stream>>>(svw, svw16, 1024 * 1024);
    wcvt<<<NW, blk, 0, stream>>>(sow, sow16, 1024 * 1024);
    wcvt<<<NW, blk, 0, stream>>>(vw,  vw16,  1024 * 1024);
    wcvt<<<NW, blk, 0, stream>>>(rw,  rw16,  1024 * 1024);
    wcvt<<<NW, blk, 0, stream>>>(ow,  ow16,  1024 * 1024);
    wcvt<<<NW, blk, 0, stream>>>(crw, crw16, 1024 * 1024);
    wcvt<<<NW, blk, 0, stream>>>(ckw, ckw16, 4096 * 1024);
    wcvt<<<NW, blk, 0, stream>>>(cvw, cvw16, 1024 * 4096);
    prep_qwT4<<<256, blk, 0, stream>>>(qw, qwT4);

    // --- time-mix ---
    mix2out<<<8192, blk, 0, stream>>>(x, n1w, tmv, tmr, bufA, bufC);  // vin, rin
    kproj<<<8192, blk, 0, stream>>>(x, n1w, skw, skb, Kt4, invn);
    attn_w<<<8192, dim3(64), 0, stream>>>(x, n1w, qwT4, qb, Kt4, invn, bufB); // y
    // t = y @ sa_v_w^T + svb
    gemm_bt<0><<<gN1024, blk, 0, stream>>>(bufB, svw16, bufD, nullptr, svb, nullptr, nullptr, 1024, 1024, 1024, 1024);
    // attnO = t @ sa_o_w^T + sob  (overwrites y, dead)
    gemm_bt<0><<<gN1024, blk, 0, stream>>>(bufD, sow16, bufB, nullptr, sob, nullptr, nullptr, 1024, 1024, 1024, 1024);
    // z = vin @ tm_value_w^T + attnO   (in-place over attnO)
    gemm_bt<1><<<gN1024, blk, 0, stream>>>(bufA, vw16, bufB, nullptr, nullptr, bufB, nullptr, 1024, 1024, 1024, 1024);
    // rkv = sigmoid(rin @ tm_recept_w^T) * z   (in-place over z)
    gemm_bt<2><<<gN1024, blk, 0, stream>>>(bufC, rw16, bufB, nullptr, nullptr, bufB, nullptr, 1024, 1024, 1024, 1024);
    // x1 = x + rkv @ tm_out_w^T   (f32, into d_out)
    gemm_bt<3><<<gN1024, blk, 0, stream>>>(bufB, ow16, nullptr, x1, nullptr, nullptr, x, 1024, 1024, 1024, 1024);

    // --- channel-mix ---
    mix2out<<<8192, blk, 0, stream>>>(x1, n2w, cmk, cmr, bufA, bufC);  // kin2, rin2
    // sig2 = sigmoid(rin2 @ cm_recept_w^T) -> D
    gemm_bt<4><<<gN1024, blk, 0, stream>>>(bufC, crw16, bufD, nullptr, nullptr, nullptr, nullptr, 1024, 1024, 1024, 1024);
    // 2 chunks of 2048 DI-columns; k2 chunk (32 MB bf16) spans bufB..bufC
    for (int c = 0; c < 2; ++c) {
        const u16* ckw_c = ckw16 + (size_t)c * 2048 * 1024;  // rows c*2048.. of (4096,1024)
        const u16* cvw_c = cvw16 + (size_t)c * 2048;         // cols c*2048.. of (1024,4096)
        gemm_bt<5><<<gN2048, blk, 0, stream>>>(bufA, ckw_c, bufB, nullptr, nullptr, nullptr, nullptr,
                                               2048, 1024, 1024, 1024);
        gemm_bt<6><<<gN1024, blk, 0, stream>>>(bufB, cvw_c, nullptr, x1, nullptr, bufD, nullptr,
                                               1024, 2048, 2048, 4096);
    }
}

// Round 9
// 1506.925 us; speedup vs baseline: 2.1933x; 1.0200x over previous
//
#include <hip/hip_runtime.h>
#include <math.h>

typedef unsigned short u16;
using short8  = __attribute__((ext_vector_type(8))) short;
using float4v = __attribute__((ext_vector_type(4))) float;

__device__ __forceinline__ float b2f(u16 u) {
    union { unsigned int i; float f; } v; v.i = ((unsigned int)u) << 16; return v.f;
}
__device__ __forceinline__ u16 f2b(float f) {
    union { float f; unsigned int i; } v; v.f = f;
    unsigned int x = v.i;
    unsigned int r = (x + 0x7fffu + ((x >> 16) & 1u)) >> 16;
    return (u16)r;
}

#define GLOAD_LDS16(gp, lp) \
    __builtin_amdgcn_global_load_lds( \
        (const __attribute__((address_space(1))) unsigned int*)(gp), \
        (__attribute__((address_space(3))) unsigned int*)(lp), 16, 0, 0)

// ---------------------------------------------------------------------------
__global__ __launch_bounds__(256) void wcvt(const float* __restrict__ s,
                                            u16* __restrict__ d, int n) {
    int stride = gridDim.x * 256;
    for (int i = blockIdx.x * 256 + threadIdx.x; i < n; i += stride)
        d[i] = f2b(s[i]);
}

// qw[64][1024] -> qwT4[d>>2][a][d&3]  (lane-coalesced float4 per 4 dims)
__global__ __launch_bounds__(256) void prep_qwT4(const float* __restrict__ qw,
                                                 float* __restrict__ qwT4) {
    int idx = blockIdx.x * 256 + threadIdx.x;   // 65536
    int a = idx >> 10, d = idx & 1023;
    qwT4[(size_t)(d >> 2) * 256 + a * 4 + (d & 3)] = qw[idx];
}

// ---------------------------------------------------------------------------
// mix2out: rmsnorm + token-shift mix, TWO mix coefficients in one pass.
// ---------------------------------------------------------------------------
__global__ __launch_bounds__(256) void mix2out(const float* __restrict__ src,
                                               const float* __restrict__ w,
                                               const float* __restrict__ f1,
                                               const float* __restrict__ f2,
                                               u16* __restrict__ out1,
                                               u16* __restrict__ out2) {
    __shared__ float redc[256], redp[256];
    int tid = threadIdx.x;
    size_t i = blockIdx.x;
    size_t ip = ((i & 4095) == 0) ? i : i - 1;
    float xc[4], xp[4];
    float ssc = 0.f, ssp = 0.f;
#pragma unroll
    for (int l = 0; l < 4; ++l) {
        int d = tid + l * 256;
        xc[l] = src[i * 1024 + d];  ssc += xc[l] * xc[l];
        xp[l] = src[ip * 1024 + d]; ssp += xp[l] * xp[l];
    }
    redc[tid] = ssc; redp[tid] = ssp; __syncthreads();
    for (int st = 128; st > 0; st >>= 1) {
        if (tid < st) { redc[tid] += redc[tid + st]; redp[tid] += redp[tid + st]; }
        __syncthreads();
    }
    float ic  = 1.f / (sqrtf(redc[0]) * (1.f / 32.f) + 1e-8f);
    float ipv = 1.f / (sqrtf(redp[0]) * (1.f / 32.f) + 1e-8f);
#pragma unroll
    for (int l = 0; l < 4; ++l) {
        int d = tid + l * 256;
        float wd = w[d];
        float xn = wd * xc[l] * ic;
        float xx = wd * xp[l] * ipv;
        float fa = f1[d], fb = f2[d];
        out1[i * 1024 + d] = f2b(fa * xn + (1.f - fa) * xx);
        out2[i * 1024 + d] = f2b(fb * xn + (1.f - fb) * xx);
    }
}

// ---------------------------------------------------------------------------
// kproj (f64 compute, f32 store in transposed Kt4 layout [b][g][key][4]).
// ---------------------------------------------------------------------------
__global__ __launch_bounds__(256) void kproj(const float* __restrict__ x,
                                             const float* __restrict__ w1,
                                             const float* __restrict__ kw,
                                             const float* __restrict__ kb,
                                             float* __restrict__ Kt4,
                                             float* __restrict__ invn) {
    __shared__ double xk[1024];
    __shared__ double red[256];
    int tid = threadIdx.x;
    size_t j = blockIdx.x;
    double ss = 0.0;
    float xc[4];
#pragma unroll
    for (int l = 0; l < 4; ++l) {
        int d = tid + l * 256;
        xc[l] = x[j * 1024 + d];
        ss += (double)xc[l] * (double)xc[l];
    }
    red[tid] = ss; __syncthreads();
    for (int st = 128; st > 0; st >>= 1) {
        if (tid < st) red[tid] += red[tid + st];
        __syncthreads();
    }
    double inv = 1.0 / (sqrt(red[0]) * (1.0 / 32.0) + 1e-8);
#pragma unroll
    for (int l = 0; l < 4; ++l) {
        int d = tid + l * 256;
        xk[d] = (double)w1[d] * (double)xc[l] * inv;
    }
    __syncthreads();
    int wv = tid >> 6, lane = tid & 63;
    int b = (int)(j >> 12), jj = (int)(j & 4095);
    for (int it = 0; it < 16; ++it) {
        int a = wv * 16 + it;
        const float* kr = kw + (size_t)a * 1024;
        double p = 0.0;
#pragma unroll
        for (int m = 0; m < 16; ++m) p += xk[lane + 64 * m] * (double)kr[lane + 64 * m];
        for (int off = 32; off; off >>= 1) p += __shfl_xor(p, off);
        if (lane == 0)
            Kt4[(((size_t)b * 16 + (a >> 2)) * 4096 + jj) * 4 + (a & 3)] = (float)(p + (double)kb[a]);
    }
    if (tid == 0) invn[j] = (float)inv;
}

// ---------------------------------------------------------------------------
// attn_w: ONE WAVE = ONE BLOCK = one query row. Zero __syncthreads.
// amdgpu_waves_per_eu(1,2): VGPR budget 256 so the 16-deep K double-buffer
// (128 VGPRs) + qreg (64) stay resident. sched_barrier(0) fences pin the
// prefetch-ahead schedule (round-8 showed the scheduler sinks prefetches to
// their use, collapsing the pipeline to depth 0 -> 35k-cycle score loop).
// Selection numerics identical to rounds 4-8 (all passing).
// ---------------------------------------------------------------------------
__global__ __attribute__((amdgpu_waves_per_eu(1, 2)))
__launch_bounds__(64) void attn_w(const float* __restrict__ x,
                                  const float* __restrict__ w1,
                                  const float* __restrict__ qwT4,
                                  const float* __restrict__ qb,
                                  const float* __restrict__ Kt4,
                                  const float* __restrict__ invn,
                                  u16* __restrict__ y) {
    __shared__ float  sc[4096];
    __shared__ double qv64s[64];
    __shared__ int    candL[40];
    __shared__ float  pwL[32];
    __shared__ int    idxL[32];

    int lane = threadIdx.x;
    int i = blockIdx.x;
    int b = i >> 12;
    int base = b << 12;

    // ---- Q projection: lane a computes Q[a]; 4 independent f64 accumulators
    const float* xr = x + (size_t)i * 1024;
    double qp0 = 0.0, qp1 = 0.0, qp2 = 0.0, qp3 = 0.0;
#pragma unroll 4
    for (int d4 = 0; d4 < 256; ++d4) {
        float4 w4  = *(const float4*)(w1 + d4 * 4);
        float4 x4  = *(const float4*)(xr + d4 * 4);
        float4 qw4 = *(const float4*)(qwT4 + (size_t)d4 * 256 + lane * 4);
        qp0 += (double)(w4.x * x4.x) * (double)qw4.x;
        qp1 += (double)(w4.y * x4.y) * (double)qw4.y;
        qp2 += (double)(w4.z * x4.z) * (double)qw4.z;
        qp3 += (double)(w4.w * x4.w) * (double)qw4.w;
    }
    double q = ((qp0 + qp1) + (qp2 + qp3)) * (double)invn[i] + (double)qb[lane];
    qv64s[lane] = q;
    float qf = (float)q;

    // broadcast all 64 q values into per-lane registers via shuffles
    float4 qreg[16];
#pragma unroll
    for (int g = 0; g < 16; ++g) {
        qreg[g].x = __shfl(qf, 4 * g + 0);
        qreg[g].y = __shfl(qf, 4 * g + 1);
        qreg[g].z = __shfl(qf, 4 * g + 2);
        qreg[g].w = __shfl(qf, 4 * g + 3);
    }

    // ---- f32 scores, double-buffered 16-wide K batches (schedule pinned) ----
    const float4* K4 = (const float4*)Kt4 + (size_t)b * 16 * 4096;
    float4 kva[16], kvb[16];
    float lv1 = -3.4e38f, lv2 = -3.4e38f;
    int   li1 = 0x7ffffffe, li2 = 0x7fffffff;
#pragma unroll
    for (int g = 0; g < 16; ++g) kva[g] = K4[g * 4096 + lane];

#define SCORE_PROC(BUF, JEXPR)                                                  \
    {                                                                           \
        int j_ = (JEXPR);                                                       \
        float s_ = 0.f;                                                         \
        _Pragma("unroll")                                                       \
        for (int g = 0; g < 16; ++g)                                            \
            s_ += qreg[g].x * BUF[g].x + qreg[g].y * BUF[g].y                   \
                + qreg[g].z * BUF[g].z + qreg[g].w * BUF[g].w;                  \
        s_ *= 0.125f;                                                           \
        if (!(s_ == s_)) s_ = -3.3e38f;                                         \
        sc[j_] = s_;                                                            \
        if (s_ > lv1 || (s_ == lv1 && j_ < li1)) {                              \
            lv2 = lv1; li2 = li1; lv1 = s_; li1 = j_;                           \
        } else if (s_ > lv2 || (s_ == lv2 && j_ < li2)) { lv2 = s_; li2 = j_; } \
    }

#pragma unroll 1
    for (int t = 0; t < 64; t += 2) {
        int j1 = (t + 1) * 64 + lane;
#pragma unroll
        for (int g = 0; g < 16; ++g) kvb[g] = K4[g * 4096 + j1];
        __builtin_amdgcn_sched_barrier(0);   // kvb loads stay ABOVE kva compute
        SCORE_PROC(kva, t * 64 + lane);
        __builtin_amdgcn_sched_barrier(0);
        if (t + 2 < 64) {
            int j2 = (t + 2) * 64 + lane;
#pragma unroll
            for (int g = 0; g < 16; ++g) kva[g] = K4[g * 4096 + j2];
        }
        __builtin_amdgcn_sched_barrier(0);   // kva loads stay ABOVE kvb compute
        SCORE_PROC(kvb, j1);
        __builtin_amdgcn_sched_barrier(0);
    }
#undef SCORE_PROC

    // ---- stage-1: extract top-40 (shuffle-only; no barriers) ----
    bool v2ok = true;
    for (int it = 0; it < 40; ++it) {
        float mv = lv1; int mi = li1;
#pragma unroll
        for (int off = 32; off >= 1; off >>= 1) {
            float ov = __shfl_xor(mv, off); int oi = __shfl_xor(mi, off);
            if (ov > mv || (ov == mv && oi < mi)) { mv = ov; mi = oi; }
        }
        if (lane == 0) candL[it] = mi;
        if (li1 == mi) {                    // this lane owned the winner
            sc[mi] = -3.4e38f;
            if (v2ok) { lv1 = lv2; li1 = li2; v2ok = false; }
            else {                           // rescan own 64 slots, fresh top-2
                lv1 = -3.4e38f; li1 = 0x7ffffffe; lv2 = -3.4e38f; li2 = 0x7fffffff;
                for (int t = 0; t < 64; ++t) {
                    int j = t * 64 + lane;
                    float v = sc[j];
                    if (v > lv1 || (v == lv1 && j < li1)) { lv2 = lv1; li2 = li1; lv1 = v; li1 = j; }
                    else if (v > lv2 || (v == lv2 && j < li2)) { lv2 = v; li2 = j; }
                }
                v2ok = true;
            }
        }
    }

    // ---- stage-2: f64 rescore of the 40 candidates ----
    int c = (lane < 40) ? lane : 0;
    int j = candL[c];
    double s = 0.0;
#pragma unroll
    for (int g = 0; g < 16; ++g) {
        float4 kv = K4[g * 4096 + j];
        s += qv64s[4 * g + 0] * (double)kv.x + qv64s[4 * g + 1] * (double)kv.y
           + qv64s[4 * g + 2] * (double)kv.z + qv64s[4 * g + 3] * (double)kv.w;
    }
    s *= 0.125;
    if (lane >= 40) { s = -1.0e300; j = 0x7fffffff; }

    // ---- exact rank among the 40 (tie -> lower key index) ----
    int rank = 0;
    for (int c2 = 0; c2 < 40; ++c2) {
        double s2 = __shfl(s, c2); int j2 = __shfl(j, c2);
        if (s2 > s || (s2 == s && j2 < j)) ++rank;
    }

    // ---- f64 softmax over ranks 0..31 ----
    unsigned long long m0 = __ballot(rank == 0);
    int src = __ffsll((unsigned long long)m0) - 1;
    double mx = __shfl(s, src);
    double e = (rank < 32) ? exp(s - mx) : 0.0;
    double sum = e;
#pragma unroll
    for (int off = 1; off < 64; off <<= 1) sum += __shfl_xor(sum, off);
    if (rank < 32) {
        pwL[rank] = (float)(e / sum) * invn[base + j];
        idxL[rank] = j;
    }

    // ---- gather (double-buffered rows, schedule pinned) ----
    float acc[16], xga[16], xgb[16];
#pragma unroll
    for (int m = 0; m < 16; ++m) acc[m] = 0.f;
    {
        const float* x0 = x + (size_t)(base + idxL[0]) * 1024;
#pragma unroll
        for (int m = 0; m < 16; ++m) xga[m] = x0[m * 64 + lane];
    }
#pragma unroll 1
    for (int k = 0; k < 32; k += 2) {
        const float* xn1 = x + (size_t)(base + idxL[k + 1]) * 1024;
#pragma unroll
        for (int m = 0; m < 16; ++m) xgb[m] = xn1[m * 64 + lane];
        __builtin_amdgcn_sched_barrier(0);
        float p0 = pwL[k];
#pragma unroll
        for (int m = 0; m < 16; ++m) acc[m] += p0 * xga[m];
        __builtin_amdgcn_sched_barrier(0);
        if (k + 2 < 32) {
            const float* xn2 = x + (size_t)(base + idxL[k + 2]) * 1024;
#pragma unroll
            for (int m = 0; m < 16; ++m) xga[m] = xn2[m * 64 + lane];
        }
        __builtin_amdgcn_sched_barrier(0);
        float p1 = pwL[k + 1];
#pragma unroll
        for (int m = 0; m < 16; ++m) acc[m] += p1 * xgb[m];
        __builtin_amdgcn_sched_barrier(0);
    }
#pragma unroll
    for (int m = 0; m < 16; ++m) {
        int d = m * 64 + lane;
        y[(size_t)i * 1024 + d] = f2b(w1[d] * acc[m]);
    }
}

// ---------------------------------------------------------------------------
// MFMA bf16 GEMM: C[M,N] = A[M,K] @ B[N,K]^T. 128x128 tile, BK=64,
// 4 waves (2x2 of 64x64), 16x16x32 MFMA, global_load_lds width-16 staging.
// EPI: 0 = bf16(acc + f32 bias[col])
//      1 = bf16(acc + bf16 aux0[g])              (in-place-safe)
//      2 = bf16(sigmoid(acc) * bf16 aux0[g])     (in-place-safe)
//      3 = f32: outF[g] = acc + f32 auxF[g]
//      4 = bf16(sigmoid(acc))
//      5 = bf16(relu(acc)^2)
//      6 = f32: outF[g] += bf16(aux0[g]) * acc   (read-modify-write)
// ---------------------------------------------------------------------------
template <int EPI>
__global__ __launch_bounds__(256) void gemm_bt(const u16* __restrict__ A,
                                               const u16* __restrict__ B,
                                               u16* outB, float* outF,
                                               const float* __restrict__ biasF,
                                               const u16* aux0,
                                               const float* auxF,
                                               int N, int K, int lda, int ldb) {
    __shared__ u16 As[128 * 64];
    __shared__ u16 Bs[128 * 64];
    int tid = threadIdx.x;
    int lane = tid & 63;
    int wv = tid >> 6;
    int row0 = blockIdx.y * 128;
    int col0 = blockIdx.x * 128;
    int wm = (wv >> 1) * 64;
    int wn = (wv & 1) * 64;
    int frow = lane & 15, quad = lane >> 4;

    float4v zero = {0.f, 0.f, 0.f, 0.f};
    float4v acc[4][4];
#pragma unroll
    for (int i = 0; i < 4; ++i)
#pragma unroll
        for (int j = 0; j < 4; ++j) acc[i][j] = zero;

    for (int k0 = 0; k0 < K; k0 += 64) {
#pragma unroll
        for (int it = 0; it < 4; ++it) {
            int base = (wv * 4 + it) * 512;      // element offset (wave-uniform)
            int e = base + lane * 8;
            int r = e >> 6, c = e & 63;
            GLOAD_LDS16(A + (size_t)(row0 + r) * lda + (k0 + c), &As[base]);
            GLOAD_LDS16(B + (size_t)(col0 + r) * ldb + (k0 + c), &Bs[base]);
        }
        __syncthreads();
#pragma unroll
        for (int kk = 0; kk < 64; kk += 32) {
            short8 a_frag[4], b_frag[4];
#pragma unroll
            for (int mi = 0; mi < 4; ++mi)
                a_frag[mi] = *(const short8*)&As[(wm + mi * 16 + frow) * 64 + kk + quad * 8];
#pragma unroll
            for (int ni = 0; ni < 4; ++ni)
                b_frag[ni] = *(const short8*)&Bs[(wn + ni * 16 + frow) * 64 + kk + quad * 8];
#pragma unroll
            for (int mi = 0; mi < 4; ++mi)
#pragma unroll
                for (int ni = 0; ni < 4; ++ni)
                    acc[mi][ni] = __builtin_amdgcn_mfma_f32_16x16x32_bf16(
                        a_frag[mi], b_frag[ni], acc[mi][ni], 0, 0, 0);
        }
        __syncthreads();
    }

#pragma unroll
    for (int mi = 0; mi < 4; ++mi) {
#pragma unroll
        for (int ni = 0; ni < 4; ++ni) {
#pragma unroll
            for (int r = 0; r < 4; ++r) {
                int row = row0 + wm + mi * 16 + quad * 4 + r;
                int col = col0 + wn + ni * 16 + frow;
                size_t g = (size_t)row * N + col;
                float v = acc[mi][ni][r];
                if constexpr (EPI == 0) {
                    outB[g] = f2b(v + biasF[col]);
                } else if constexpr (EPI == 1) {
                    outB[g] = f2b(v + b2f(aux0[g]));
                } else if constexpr (EPI == 2) {
                    float sg = 1.f / (1.f + expf(-v));
                    outB[g] = f2b(sg * b2f(aux0[g]));
                } else if constexpr (EPI == 3) {
                    outF[g] = v + auxF[g];
                } else if constexpr (EPI == 4) {
                    outB[g] = f2b(1.f / (1.f + expf(-v)));
                } else if constexpr (EPI == 5) {
                    float t = v > 0.f ? v : 0.f;
                    outB[g] = f2b(t * t);
                } else if constexpr (EPI == 6) {
                    outF[g] = outF[g] + b2f(aux0[g]) * v;
                }
            }
        }
    }
}

// ---------------------------------------------------------------------------
extern "C" void kernel_launch(void* const* d_in, const int* in_sizes, int n_in,
                              void* d_out, int out_size, void* d_ws, size_t ws_size,
                              hipStream_t stream) {
    (void)in_sizes; (void)n_in; (void)out_size; (void)ws_size;
    const float* x   = (const float*)d_in[0];
    const float* n1w = (const float*)d_in[1];
    // d_in[2] tm_mix_k, d_in[5] tm_key_w are dead in the reference
    const float* tmv = (const float*)d_in[3];
    const float* tmr = (const float*)d_in[4];
    const float* vw  = (const float*)d_in[6];
    const float* rw  = (const float*)d_in[7];
    const float* ow  = (const float*)d_in[8];
    const float* qw  = (const float*)d_in[9];
    const float* qb  = (const float*)d_in[10];
    const float* skw = (const float*)d_in[11];
    const float* skb = (const float*)d_in[12];
    const float* svw = (const float*)d_in[13];
    const float* svb = (const float*)d_in[14];
    const float* sow = (const float*)d_in[15];
    const float* sob = (const float*)d_in[16];
    const float* n2w = (const float*)d_in[17];
    const float* cmk = (const float*)d_in[18];
    const float* cmr = (const float*)d_in[19];
    const float* ckw = (const float*)d_in[20];
    const float* crw = (const float*)d_in[21];
    const float* cvw = (const float*)d_in[22];

    char* W = (char*)d_ws;
    const size_t MB = 1ull << 20;
    u16*   bufA  = (u16*)(W + 0 * MB);     // 16 MB
    u16*   bufB  = (u16*)(W + 16 * MB);    // 16 MB (with C forms 32 MB k2 chunk)
    u16*   bufC  = (u16*)(W + 32 * MB);    // 16 MB
    u16*   bufD  = (u16*)(W + 48 * MB);    // 16 MB
    float* Kt4   = (float*)(W + 64 * MB);  // 2 MB  [b][g][key][4]
    float* invn  = (float*)(W + 66 * MB);  // 32 KB
    float* qwT4  = (float*)(W + 67 * MB);  // 256 KB
    u16*   ckw16 = (u16*)(W + 68 * MB);    // 8 MB
    u16*   cvw16 = (u16*)(W + 76 * MB);    // 8 MB
    u16*   svw16 = (u16*)(W + 84 * MB);    // 2 MB each below
    u16*   sow16 = (u16*)(W + 86 * MB);
    u16*   vw16  = (u16*)(W + 88 * MB);
    u16*   rw16  = (u16*)(W + 90 * MB);
    u16*   ow16  = (u16*)(W + 92 * MB);
    u16*   crw16 = (u16*)(W + 94 * MB);    // peak 96 MB
    float* x1    = (float*)d_out;          // 32 MB f32, accumulated in place

    dim3 blk(256);
    dim3 gN1024(8, 64);
    dim3 gN2048(16, 64);
    const int NW = 512;

    // weight prep
    wcvt<<<NW, blk, 0, stream>>>(svw, svw16, 1024 * 1024);
    wcvt<<<NW, blk, 0, stream>>>(sow, sow16, 1024 * 1024);
    wcvt<<<NW, blk, 0, stream>>>(vw,  vw16,  1024 * 1024);
    wcvt<<<NW, blk, 0, stream>>>(rw,  rw16,  1024 * 1024);
    wcvt<<<NW, blk, 0, stream>>>(ow,  ow16,  1024 * 1024);
    wcvt<<<NW, blk, 0, stream>>>(crw, crw16, 1024 * 1024);
    wcvt<<<NW, blk, 0, stream>>>(ckw, ckw16, 4096 * 1024);
    wcvt<<<NW, blk, 0, stream>>>(cvw, cvw16, 1024 * 4096);
    prep_qwT4<<<256, blk, 0, stream>>>(qw, qwT4);

    // --- time-mix ---
    mix2out<<<8192, blk, 0, stream>>>(x, n1w, tmv, tmr, bufA, bufC);  // vin, rin
    kproj<<<8192, blk, 0, stream>>>(x, n1w, skw, skb, Kt4, invn);
    attn_w<<<8192, dim3(64), 0, stream>>>(x, n1w, qwT4, qb, Kt4, invn, bufB); // y
    // t = y @ sa_v_w^T + svb
    gemm_bt<0><<<gN1024, blk, 0, stream>>>(bufB, svw16, bufD, nullptr, svb, nullptr, nullptr, 1024, 1024, 1024, 1024);
    // attnO = t @ sa_o_w^T + sob  (overwrites y, dead)
    gemm_bt<0><<<gN1024, blk, 0, stream>>>(bufD, sow16, bufB, nullptr, sob, nullptr, nullptr, 1024, 1024, 1024, 1024);
    // z = vin @ tm_value_w^T + attnO   (in-place over attnO)
    gemm_bt<1><<<gN1024, blk, 0, stream>>>(bufA, vw16, bufB, nullptr, nullptr, bufB, nullptr, 1024, 1024, 1024, 1024);
    // rkv = sigmoid(rin @ tm_recept_w^T) * z   (in-place over z)
    gemm_bt<2><<<gN1024, blk, 0, stream>>>(bufC, rw16, bufB, nullptr, nullptr, bufB, nullptr, 1024, 1024, 1024, 1024);
    // x1 = x + rkv @ tm_out_w^T   (f32, into d_out)
    gemm_bt<3><<<gN1024, blk, 0, stream>>>(bufB, ow16, nullptr, x1, nullptr, nullptr, x, 1024, 1024, 1024, 1024);

    // --- channel-mix ---
    mix2out<<<8192, blk, 0, stream>>>(x1, n2w, cmk, cmr, bufA, bufC);  // kin2, rin2
    // sig2 = sigmoid(rin2 @ cm_recept_w^T) -> D
    gemm_bt<4><<<gN1024, blk, 0, stream>>>(bufC, crw16, bufD, nullptr, nullptr, nullptr, nullptr, 1024, 1024, 1024, 1024);
    // 2 chunks of 2048 DI-columns; k2 chunk (32 MB bf16) spans bufB..bufC
    for (int c = 0; c < 2; ++c) {
        const u16* ckw_c = ckw16 + (size_t)c * 2048 * 1024;  // rows c*2048.. of (4096,1024)
        const u16* cvw_c = cvw16 + (size_t)c * 2048;         // cols c*2048.. of (1024,4096)
        gemm_bt<5><<<gN2048, blk, 0, stream>>>(bufA, ckw_c, bufB, nullptr, nullptr, nullptr, nullptr,
                                               2048, 1024, 1024, 1024);
        gemm_bt<6><<<gN1024, blk, 0, stream>>>(bufB, cvw_c, nullptr, x1, nullptr, bufD, nullptr,
                                               1024, 2048, 2048, 4096);
    }
}